// Round 3
// baseline (7492.232 us; speedup 1.0000x reference)
//
#include <hip/hip_runtime.h>
#include <math.h>

#define BB 64
#define SS 128
#define DD 1024
#define HH 512
#define EE 512
#define VV 32000
#define NSTEP 31
#define G4 2048        // 4*H
#define XDIM 1536      // E + D_enc

// ---------------- workspace layout (in floats) ----------------
#define OFF_KEYS   0L                                  // W2/v2/b2/s0
#define OFF_K2     8388608L
#define OFF_SB     12582912L
#define OFF_MA     12591104L
#define OFF_STATE  12599296L                           // h0,c0,h1,c1 (131072)
#define OFF_X      12730368L
#define OFF_P      12828672L
#define OFF_PRED   14925824L
#define OFF_WH     14925888L
#define OFF_WL     23117888L
#define OFF_H1H    31309888L
#define OFF_H1L    31326272L
#define OFF_LOG    31342656L                           // 63488000
#define TOTAL_BUF  94830656L
#define TOTAL_FB   31342656L
// ---- fused-MFMA LSTM extras (beyond TOTAL_BUF) ----
#define OFF_WC0H   94830656L                           // 2048x2048 bf16 hi (2097152 fl)
#define OFF_WC0L   96927808L
#define OFF_WC1H   99024960L                           // 2048x1024 bf16 hi (1048576 fl)
#define OFF_WC1L   100073536L
#define OFF_A0     101122112L                          // 2 par x (hi 65536 + lo 65536) fl
#define OFF_A1     101384256L                          // 2 par x (hi 32768 + lo 32768) fl
#define TOTAL_MF   101515328L

typedef __attribute__((ext_vector_type(8))) short short8;
typedef __attribute__((ext_vector_type(4))) float float4v;

__device__ __forceinline__ unsigned short bf16_rne(float v)
{
    unsigned u = __float_as_uint(v);
    unsigned r = (u + 0x7FFF + ((u >> 16) & 1)) >> 16;
    return (unsigned short)r;
}

// =====================================================================
// Generic fp32 GEMM (K2 gemm + logits fallback)
// =====================================================================
template<int BT>
__global__ __launch_bounds__(256)
void gemm_kernel(const float* __restrict__ A, const float* __restrict__ Bm,
                 const float* __restrict__ bias, float* __restrict__ C,
                 int M, int N, int K, long ldm, long ldn, long coff)
{
    __shared__ float As[32][68];
    __shared__ float Bs[32][132];
    int tid = threadIdx.x;
    int tx = tid & 15, ty = tid >> 4;
    int m0 = blockIdx.y * 64, n0 = blockIdx.x * 128;

    float acc[4][8];
#pragma unroll
    for (int i = 0; i < 4; ++i)
#pragma unroll
        for (int j = 0; j < 8; ++j) acc[i][j] = 0.0f;

    int ar = tid >> 3;          // 0..31
    int ac = (tid & 7) * 4;     // 0,4,...,28

    for (int kk = 0; kk < K; kk += 32) {
#pragma unroll
        for (int p = 0; p < 2; ++p) {
            int r = ar + p * 32;
            float4 v = *(const float4*)(A + (long)(m0 + r) * K + kk + ac);
            As[ac + 0][r] = v.x; As[ac + 1][r] = v.y;
            As[ac + 2][r] = v.z; As[ac + 3][r] = v.w;
        }
        if (BT) {
#pragma unroll
            for (int p = 0; p < 4; ++p) {
                int n = ar + p * 32;
                float4 v = *(const float4*)(Bm + (long)(n0 + n) * K + kk + ac);
                Bs[ac + 0][n] = v.x; Bs[ac + 1][n] = v.y;
                Bs[ac + 2][n] = v.z; Bs[ac + 3][n] = v.w;
            }
        } else {
            int bn = (tid & 31) * 4;
            int bk = tid >> 5;
#pragma unroll
            for (int p = 0; p < 4; ++p) {
                int k = bk + p * 8;
                float4 v = *(const float4*)(Bm + (long)(kk + k) * N + n0 + bn);
                *(float4*)&Bs[k][bn] = v;
            }
        }
        __syncthreads();
#pragma unroll
        for (int k = 0; k < 32; ++k) {
            float4 a  = *(const float4*)&As[k][ty * 4];
            float4 b0 = *(const float4*)&Bs[k][tx * 8];
            float4 b1 = *(const float4*)&Bs[k][tx * 8 + 4];
            float av[4] = {a.x, a.y, a.z, a.w};
            float bv[8] = {b0.x, b0.y, b0.z, b0.w, b1.x, b1.y, b1.z, b1.w};
#pragma unroll
            for (int im = 0; im < 4; ++im)
#pragma unroll
                for (int in = 0; in < 8; ++in)
                    acc[im][in] = fmaf(av[im], bv[in], acc[im][in]);
        }
        __syncthreads();
    }

#pragma unroll
    for (int im = 0; im < 4; ++im) {
        int m = m0 + ty * 4 + im;
#pragma unroll
        for (int in = 0; in < 8; ++in) {
            int n = n0 + tx * 8 + in;
            float r = acc[im][in];
            if (bias) r += bias[n];
            C[coff + (long)m * ldm + (long)n * ldn] = r;
        }
    }
}

// =====================================================================
// W2 = wk^T @ wq   (TN gemm)
// =====================================================================
__global__ __launch_bounds__(256)
void w2_gemm(const float* __restrict__ wk, const float* __restrict__ wq,
             float* __restrict__ W2)
{
    __shared__ float As[32][36];
    __shared__ float Bs[32][68];
    int tid = threadIdx.x;
    int d0 = blockIdx.y * 32, h0 = blockIdx.x * 64;
    int tx = tid & 15, ty = tid >> 4;

    float acc[2][4];
#pragma unroll
    for (int i = 0; i < 2; ++i)
#pragma unroll
        for (int j = 0; j < 4; ++j) acc[i][j] = 0.0f;

    int le = tid >> 3;
    int ld = (tid & 7) * 4;
    int lh = (tid & 7) * 8;

    for (int e0 = 0; e0 < DD; e0 += 32) {
        float4 va = *(const float4*)(wk + (long)(e0 + le) * DD + d0 + ld);
        *(float4*)&As[le][ld] = va;
        float4 vb0 = *(const float4*)(wq + (long)(e0 + le) * HH + h0 + lh);
        float4 vb1 = *(const float4*)(wq + (long)(e0 + le) * HH + h0 + lh + 4);
        *(float4*)&Bs[le][lh] = vb0;
        *(float4*)&Bs[le][lh + 4] = vb1;
        __syncthreads();
#pragma unroll
        for (int k = 0; k < 32; ++k) {
            float a0 = As[k][ty * 2];
            float a1 = As[k][ty * 2 + 1];
            float4 b = *(const float4*)&Bs[k][tx * 4];
            float bv[4] = {b.x, b.y, b.z, b.w};
#pragma unroll
            for (int j = 0; j < 4; ++j) {
                acc[0][j] = fmaf(a0, bv[j], acc[0][j]);
                acc[1][j] = fmaf(a1, bv[j], acc[1][j]);
            }
        }
        __syncthreads();
    }
#pragma unroll
    for (int i = 0; i < 2; ++i)
#pragma unroll
        for (int j = 0; j < 4; ++j)
            W2[(long)(d0 + ty * 2 + i) * HH + h0 + tx * 4 + j] = acc[i][j];
}

// v2[d] = wk^T @ bq ; b2[h] = bk @ wq ; s0 = bk . bq
__global__ __launch_bounds__(256)
void prep_vecs(const float* __restrict__ wk, const float* __restrict__ wq,
               const float* __restrict__ bq, const float* __restrict__ bk,
               float* __restrict__ v2, float* __restrict__ b2,
               float* __restrict__ s0)
{
    int idx = blockIdx.x * 256 + threadIdx.x;
    if (idx < DD) {
        float a = 0;
        for (int e = 0; e < DD; ++e) a += wk[(long)e * DD + idx] * bq[e];
        v2[idx] = a;
    } else if (idx < DD + HH) {
        int h = idx - DD;
        float a = 0;
        for (int e = 0; e < DD; ++e) a += bk[e] * wq[(long)e * HH + h];
        b2[h] = a;
    } else if (idx == DD + HH) {
        float a = 0;
        for (int e = 0; e < DD; ++e) a += bk[e] * bq[e];
        *s0 = a;
    }
}

// ---- bf16 hi/lo split of an fp32 array ----
__global__ __launch_bounds__(256)
void split_kernel(const float* __restrict__ x, unsigned short* __restrict__ hi,
                  unsigned short* __restrict__ lo, int n)
{
    int i = (blockIdx.x * 256 + threadIdx.x) * 4;
    if (i >= n) return;
    float4 v = *(const float4*)(x + i);
    float vv[4] = {v.x, v.y, v.z, v.w};
    unsigned hpack[2], lpack[2];
#pragma unroll
    for (int p = 0; p < 2; ++p) {
        unsigned short h0 = bf16_rne(vv[2 * p]);
        unsigned short h1 = bf16_rne(vv[2 * p + 1]);
        float f0 = __uint_as_float((unsigned)h0 << 16);
        float f1 = __uint_as_float((unsigned)h1 << 16);
        unsigned short l0 = bf16_rne(vv[2 * p] - f0);
        unsigned short l1 = bf16_rne(vv[2 * p + 1] - f1);
        hpack[p] = (unsigned)h0 | ((unsigned)h1 << 16);
        lpack[p] = (unsigned)l0 | ((unsigned)l1 << 16);
    }
    *(uint2*)(hi + i) = make_uint2(hpack[0], hpack[1]);
    *(uint2*)(lo + i) = make_uint2(lpack[0], lpack[1]);
}

// ---- concat two row-major fp32 matrices along K, bf16 hi/lo split ----
// out row n, col k: k<K1 -> s1[n][k], else s2[n][k-K1]. Kt = K1+K2.
__global__ __launch_bounds__(256)
void cat_split(const float* __restrict__ s1, int K1, const float* __restrict__ s2,
               int Kt, unsigned short* __restrict__ hi, unsigned short* __restrict__ lo,
               int total)
{
    int e = (blockIdx.x * 256 + threadIdx.x) * 4;
    if (e >= total) return;
    int n = e / Kt, k = e - n * Kt;
    const float* src = (k < K1) ? (s1 + (long)n * K1 + k)
                                : (s2 + (long)n * (Kt - K1) + (k - K1));
    float4 v = *(const float4*)src;
    float vv[4] = {v.x, v.y, v.z, v.w};
    unsigned hpack[2], lpack[2];
#pragma unroll
    for (int p = 0; p < 2; ++p) {
        unsigned short h0 = bf16_rne(vv[2 * p]);
        unsigned short h1 = bf16_rne(vv[2 * p + 1]);
        float f0 = __uint_as_float((unsigned)h0 << 16);
        float f1 = __uint_as_float((unsigned)h1 << 16);
        unsigned short l0 = bf16_rne(vv[2 * p] - f0);
        unsigned short l1 = bf16_rne(vv[2 * p + 1] - f1);
        hpack[p] = (unsigned)h0 | ((unsigned)h1 << 16);
        lpack[p] = (unsigned)l0 | ((unsigned)l1 << 16);
    }
    *(uint2*)(hi + e) = make_uint2(hpack[0], hpack[1]);
    *(uint2*)(lo + e) = make_uint2(lpack[0], lpack[1]);
}

__global__ __launch_bounds__(256)
void zero_a(float* __restrict__ p)
{
    p[blockIdx.x * 256 + threadIdx.x] = 0.0f;
}

// =====================================================================
// Logits GEMM via bf16-split MFMA (3-term): C(64,32000) = h1 @ w_out^T
// =====================================================================
__global__ __launch_bounds__(256)
void logits_mfma(const unsigned short* __restrict__ Ah, const unsigned short* __restrict__ Al,
                 const unsigned short* __restrict__ Bh, const unsigned short* __restrict__ Bl,
                 const float* __restrict__ bias, float* __restrict__ C,
                 long ldm, long ldn, long coff)
{
    int tid = threadIdx.x;
    int wid = tid >> 6, lane = tid & 63;
    int ln = lane & 15, q = lane >> 4;
    int nb = blockIdx.x * 128 + wid * 32;

    float4v acc[4][2];
#pragma unroll
    for (int mf = 0; mf < 4; ++mf)
#pragma unroll
        for (int nf = 0; nf < 2; ++nf)
            acc[mf][nf] = (float4v){0.f, 0.f, 0.f, 0.f};

    const int kb = q * 8;
#pragma unroll 2
    for (int k0 = 0; k0 < 512; k0 += 32) {
        long ko = k0 + kb;
        short8 a_h[4], a_l[4], b_h[2], b_l[2];
#pragma unroll
        for (int nf = 0; nf < 2; ++nf) {
            long row = (long)(nb + nf * 16 + ln) * 512 + ko;
            b_h[nf] = *(const short8*)(Bh + row);
            b_l[nf] = *(const short8*)(Bl + row);
        }
#pragma unroll
        for (int mf = 0; mf < 4; ++mf) {
            long row = (long)(mf * 16 + ln) * 512 + ko;
            a_h[mf] = *(const short8*)(Ah + row);
            a_l[mf] = *(const short8*)(Al + row);
        }
#pragma unroll
        for (int mf = 0; mf < 4; ++mf)
#pragma unroll
            for (int nf = 0; nf < 2; ++nf) {
                acc[mf][nf] = __builtin_amdgcn_mfma_f32_16x16x32_bf16(a_h[mf], b_h[nf], acc[mf][nf], 0, 0, 0);
                acc[mf][nf] = __builtin_amdgcn_mfma_f32_16x16x32_bf16(a_l[mf], b_h[nf], acc[mf][nf], 0, 0, 0);
                acc[mf][nf] = __builtin_amdgcn_mfma_f32_16x16x32_bf16(a_h[mf], b_l[nf], acc[mf][nf], 0, 0, 0);
            }
    }

#pragma unroll
    for (int nf = 0; nf < 2; ++nf) {
        int n = nb + nf * 16 + ln;
        float bo = bias[n];
#pragma unroll
        for (int mf = 0; mf < 4; ++mf)
#pragma unroll
            for (int r = 0; r < 4; ++r) {
                int m = mf * 16 + q * 4 + r;
                C[coff + (long)m * ldm + (long)n * ldn] = acc[mf][nf][r] + bo;
            }
    }
}

// =====================================================================
// Fused LSTM layer: gates GEMM (bf16-split 4-term MFMA) + activations.
// A: [64][KK] bf16 hi/lo ([x|h] concat). W: [2048][KK] bf16 hi/lo
// ([w_ih|w_hh] concat). Grid 32 blocks x 256 thr; block = 16 h-columns
// (jf), wave = one gate (i/f/g/o). Epilogue: LDS gate exchange, cell
// update, h emitted as bf16 hi/lo to up to two destinations.
// =====================================================================
template<int KK>
__global__ __launch_bounds__(256)
void gates_mfma(const unsigned short* __restrict__ Ah, const unsigned short* __restrict__ Al,
                const unsigned short* __restrict__ Wh, const unsigned short* __restrict__ Wl,
                const float* __restrict__ b_ih, const float* __restrict__ b_hh,
                float* __restrict__ c, float* __restrict__ hout,
                unsigned short* __restrict__ d1h, unsigned short* __restrict__ d1l,
                int d1ld, int d1off,
                unsigned short* __restrict__ d2h, unsigned short* __restrict__ d2l,
                int d2ld, int d2off)
{
    __shared__ float gacc[4][64][17];
    int tid = threadIdx.x;
    int wid = tid >> 6, lane = tid & 63;
    int ln = lane & 15, q = lane >> 4;
    int jf = blockIdx.x;              // 0..31 -> h-cols [jf*16, jf*16+16)
    int j0 = jf * 16;
    long wrow = (long)(wid * 512 + j0 + ln) * KK;

    float4v acc[4];
#pragma unroll
    for (int mf = 0; mf < 4; ++mf) acc[mf] = (float4v){0.f, 0.f, 0.f, 0.f};

    const int kb = q * 8;
#pragma unroll 2
    for (int k0 = 0; k0 < KK; k0 += 32) {
        long ko = k0 + kb;
        short8 b_h = *(const short8*)(Wh + wrow + ko);
        short8 b_l = *(const short8*)(Wl + wrow + ko);
        short8 a_h[4], a_l[4];
#pragma unroll
        for (int mf = 0; mf < 4; ++mf) {
            long arow = (long)(mf * 16 + ln) * KK + ko;
            a_h[mf] = *(const short8*)(Ah + arow);
            a_l[mf] = *(const short8*)(Al + arow);
        }
#pragma unroll
        for (int mf = 0; mf < 4; ++mf) {
            acc[mf] = __builtin_amdgcn_mfma_f32_16x16x32_bf16(a_h[mf], b_h, acc[mf], 0, 0, 0);
            acc[mf] = __builtin_amdgcn_mfma_f32_16x16x32_bf16(a_l[mf], b_h, acc[mf], 0, 0, 0);
            acc[mf] = __builtin_amdgcn_mfma_f32_16x16x32_bf16(a_h[mf], b_l, acc[mf], 0, 0, 0);
            acc[mf] = __builtin_amdgcn_mfma_f32_16x16x32_bf16(a_l[mf], b_l, acc[mf], 0, 0, 0);
        }
    }

#pragma unroll
    for (int mf = 0; mf < 4; ++mf)
#pragma unroll
        for (int r = 0; r < 4; ++r)
            gacc[wid][mf * 16 + q * 4 + r][ln] = acc[mf][r];
    __syncthreads();

    // act: thread -> batch m = tid>>2, 4 h-cols
    int m = tid >> 2, jj = (tid & 3) * 4;
#pragma unroll
    for (int u = 0; u < 4; ++u) {
        int j = jj + u;
        int col = j0 + j;                      // 0..511
        float gi = gacc[0][m][j] + b_ih[col] + b_hh[col];
        float gf = gacc[1][m][j] + b_ih[HH + col] + b_hh[HH + col];
        float gg = gacc[2][m][j] + b_ih[2 * HH + col] + b_hh[2 * HH + col];
        float go = gacc[3][m][j] + b_ih[3 * HH + col] + b_hh[3 * HH + col];
        float i_ = 1.0f / (1.0f + expf(-gi));
        float f_ = 1.0f / (1.0f + expf(-gf));
        float g_ = tanhf(gg);
        float o_ = 1.0f / (1.0f + expf(-go));
        int ci = m * HH + col;
        float cn = f_ * c[ci] + i_ * g_;
        c[ci] = cn;
        float hv = o_ * tanhf(cn);
        if (hout) hout[ci] = hv;
        unsigned short hb = bf16_rne(hv);
        float hf = __uint_as_float((unsigned)hb << 16);
        unsigned short lb = bf16_rne(hv - hf);
        d1h[m * d1ld + d1off + col] = hb;
        d1l[m * d1ld + d1off + col] = lb;
        if (d2h) {
            d2h[m * d2ld + d2off + col] = hb;
            d2l[m * d2ld + d2off + col] = lb;
        }
    }
}

// =====================================================================
// LSTM gates split-K GEMM (fallback path)
// =====================================================================
__global__ __launch_bounds__(256)
void lstm_gates(const float* __restrict__ A1, int K1, const float* __restrict__ B1,
                const float* __restrict__ A2, int K2c, const float* __restrict__ B2,
                int z1, float* __restrict__ P)
{
    __shared__ float As[32][68];
    __shared__ float Bs[32][132];
    int tid = threadIdx.x;
    int tx = tid & 15, ty = tid >> 4;
    int n0 = blockIdx.x * 128;
    int z = blockIdx.y;

    const float* A; const float* Bw; int kb, lda;
    if (z < z1) { A = A1; Bw = B1; kb = z * 128;        lda = K1; }
    else        { A = A2; Bw = B2; kb = (z - z1) * 128; lda = K2c; }

    float acc[4][8];
#pragma unroll
    for (int i = 0; i < 4; ++i)
#pragma unroll
        for (int j = 0; j < 8; ++j) acc[i][j] = 0.0f;

    int ar = tid >> 3;
    int ac = (tid & 7) * 4;

    for (int kk = kb; kk < kb + 128; kk += 32) {
#pragma unroll
        for (int p = 0; p < 2; ++p) {
            int r = ar + p * 32;
            float4 v = *(const float4*)(A + (long)r * lda + kk + ac);
            As[ac + 0][r] = v.x; As[ac + 1][r] = v.y;
            As[ac + 2][r] = v.z; As[ac + 3][r] = v.w;
        }
#pragma unroll
        for (int p = 0; p < 4; ++p) {
            int n = ar + p * 32;
            float4 v = *(const float4*)(Bw + (long)(n0 + n) * lda + kk + ac);
            Bs[ac + 0][n] = v.x; Bs[ac + 1][n] = v.y;
            Bs[ac + 2][n] = v.z; Bs[ac + 3][n] = v.w;
        }
        __syncthreads();
#pragma unroll
        for (int k = 0; k < 32; ++k) {
            float4 a  = *(const float4*)&As[k][ty * 4];
            float4 b0 = *(const float4*)&Bs[k][tx * 8];
            float4 b1 = *(const float4*)&Bs[k][tx * 8 + 4];
            float av[4] = {a.x, a.y, a.z, a.w};
            float bv[8] = {b0.x, b0.y, b0.z, b0.w, b1.x, b1.y, b1.z, b1.w};
#pragma unroll
            for (int im = 0; im < 4; ++im)
#pragma unroll
                for (int in = 0; in < 8; ++in)
                    acc[im][in] = fmaf(av[im], bv[in], acc[im][in]);
        }
        __syncthreads();
    }

    float* Pp = P + (long)z * (BB * (long)G4);
#pragma unroll
    for (int im = 0; im < 4; ++im) {
        int m = ty * 4 + im;
#pragma unroll
        for (int in = 0; in < 8; ++in)
            Pp[(long)m * G4 + n0 + tx * 8 + in] = acc[im][in];
    }
}

// ---- fallback act ----
__global__ __launch_bounds__(256)
void lstm_act(const float* __restrict__ P, int z,
              const float* __restrict__ b_ih, const float* __restrict__ b_hh,
              float* __restrict__ c, float* __restrict__ h,
              unsigned short* __restrict__ hh, unsigned short* __restrict__ hl)
{
    int idx = blockIdx.x * 256 + threadIdx.x;
    int b = idx >> 9, j = idx & 511;
    float gi = 0, gf = 0, gg = 0, go = 0;
    for (int zi = 0; zi < z; ++zi) {
        const float* p = P + (long)zi * (BB * (long)G4) + (long)b * G4 + j;
        gi += p[0]; gf += p[HH]; gg += p[2 * HH]; go += p[3 * HH];
    }
    gi += b_ih[j] + b_hh[j];
    gf += b_ih[HH + j] + b_hh[HH + j];
    gg += b_ih[2 * HH + j] + b_hh[2 * HH + j];
    go += b_ih[3 * HH + j] + b_hh[3 * HH + j];
    float i_ = 1.0f / (1.0f + expf(-gi));
    float f_ = 1.0f / (1.0f + expf(-gf));
    float g_ = tanhf(gg);
    float o_ = 1.0f / (1.0f + expf(-go));
    float cn = f_ * c[idx] + i_ * g_;
    c[idx] = cn;
    float hv = o_ * tanhf(cn);
    h[idx] = hv;
    if (hh) {
        unsigned short hb = bf16_rne(hv);
        float hf = __uint_as_float((unsigned)hb << 16);
        hh[idx] = hb;
        hl[idx] = bf16_rne(hv - hf);
    }
}

// ---- fused: embedding gather + attention, 4-way d-chunked ctx ----
// Optionally also emits x as bf16 hi/lo into A0 (cols [0,1536)).
__global__ __launch_bounds__(256)
void attn_embed(const float* __restrict__ h1, const float* __restrict__ K2,
                const float* __restrict__ sb, const float* __restrict__ mA,
                const float* __restrict__ enc, const float* __restrict__ emb,
                const int* __restrict__ pred, float* __restrict__ x,
                unsigned short* __restrict__ a0h, unsigned short* __restrict__ a0l)
{
    __shared__ float shH[512];
    __shared__ float shP[256];
    __shared__ float shS[128];
    __shared__ float shR[64];
    int blk = blockIdx.x;
    int b = blk >> 2, ch = blk & 3;
    int tid = threadIdx.x;

    shH[tid]       = h1[b * HH + tid];
    shH[tid + 256] = h1[b * HH + 256 + tid];
    float* xr = x + (long)b * XDIM;
    if (ch == 0) {
        const float* et = emb + (long)pred[b] * EE;
        float v0 = et[tid], v1 = et[tid + 256];
        xr[tid]       = v0;
        xr[tid + 256] = v1;
        if (a0h) {
            unsigned short h0b = bf16_rne(v0);
            unsigned short h1b = bf16_rne(v1);
            a0h[b * 2048 + tid]       = h0b;
            a0h[b * 2048 + tid + 256] = h1b;
            a0l[b * 2048 + tid]       = bf16_rne(v0 - __uint_as_float((unsigned)h0b << 16));
            a0l[b * 2048 + tid + 256] = bf16_rne(v1 - __uint_as_float((unsigned)h1b << 16));
        }
    }
    __syncthreads();

    {
        int s = tid >> 1, hf = tid & 1;
        const float* kp = K2 + ((long)(b * SS + s)) * HH + hf * 256;
        const float* hp = shH + hf * 256;
        float a = 0;
        for (int j = 0; j < 256; j += 4) {
            float4 v = *(const float4*)(kp + j);
            a += hp[j] * v.x + hp[j + 1] * v.y + hp[j + 2] * v.z + hp[j + 3] * v.w;
        }
        shP[tid] = a;
    }
    __syncthreads();
    if (tid < 128) {
        float sc = (shP[2 * tid] + shP[2 * tid + 1] + sb[b * SS + tid]) * 0.03125f
                   + mA[b * SS + tid];
        shS[tid] = sc;
    }
    __syncthreads();
    if (tid < 64) shR[tid] = fmaxf(shS[tid], shS[tid + 64]);
    __syncthreads();
    if (tid < 32) shR[tid] = fmaxf(shR[tid], shR[tid + 32]);
    __syncthreads();
    if (tid < 16) shR[tid] = fmaxf(shR[tid], shR[tid + 16]);
    __syncthreads();
    if (tid < 8)  shR[tid] = fmaxf(shR[tid], shR[tid + 8]);
    __syncthreads();
    if (tid < 4)  shR[tid] = fmaxf(shR[tid], shR[tid + 4]);
    __syncthreads();
    if (tid < 2)  shR[tid] = fmaxf(shR[tid], shR[tid + 2]);
    __syncthreads();
    if (tid == 0) shR[0] = fmaxf(shR[0], shR[1]);
    __syncthreads();
    float mx = shR[0];
    __syncthreads();
    if (tid < 128) shS[tid] = expf(shS[tid] - mx);
    __syncthreads();
    if (tid < 64) shR[tid] = shS[tid] + shS[tid + 64];
    __syncthreads();
    if (tid < 32) shR[tid] += shR[tid + 32];
    __syncthreads();
    if (tid < 16) shR[tid] += shR[tid + 16];
    __syncthreads();
    if (tid < 8)  shR[tid] += shR[tid + 8];
    __syncthreads();
    if (tid < 4)  shR[tid] += shR[tid + 4];
    __syncthreads();
    if (tid < 2)  shR[tid] += shR[tid + 2];
    __syncthreads();
    if (tid == 0) shR[0] += shR[1];
    __syncthreads();
    float inv = 1.0f / shR[0];
    if (tid < 128) shS[tid] *= inv;
    __syncthreads();

    const float* ep = enc + (long)b * SS * DD + ch * 256 + tid;
    float a = 0;
#pragma unroll 4
    for (int s = 0; s < SS; ++s)
        a += shS[s] * ep[(long)s * DD];
    int col = EE + ch * 256 + tid;
    xr[col] = a;
    if (a0h) {
        unsigned short hb = bf16_rne(a);
        a0h[b * 2048 + col] = hb;
        a0l[b * 2048 + col] = bf16_rne(a - __uint_as_float((unsigned)hb << 16));
    }
}

// ---- greedy argmax (first max) ----
__global__ __launch_bounds__(256)
void argmax_kernel(const float* __restrict__ L, long rowStride, long vStride,
                   int* __restrict__ pred)
{
    __shared__ float shV[256];
    __shared__ int   shI[256];
    int b = blockIdx.x, tid = threadIdx.x;
    const float* p = L + (long)b * rowStride;
    float best = -INFINITY; int bi = 0;
    for (int v = tid; v < VV; v += 256) {
        float val = p[(long)v * vStride];
        if (val > best) { best = val; bi = v; }
    }
    shV[tid] = best; shI[tid] = bi;
    __syncthreads();
    for (int o = 128; o > 0; o >>= 1) {
        if (tid < o) {
            float ov = shV[tid + o]; int oi = shI[tid + o];
            if (ov > shV[tid] || (ov == shV[tid] && oi < shI[tid])) {
                shV[tid] = ov; shI[tid] = oi;
            }
        }
        __syncthreads();
    }
    if (tid == 0) pred[b] = shI[0];
}

// ---- (T,B,V) -> (B,V,T) transpose via LDS ----
__global__ __launch_bounds__(256)
void transpose_out(const float* __restrict__ Lall, float* __restrict__ out)
{
    __shared__ float tile[NSTEP][129];
    int b = blockIdx.x, v0 = blockIdx.y * 128, tid = threadIdx.x;
    int i = tid & 127, th = tid >> 7;
    for (int tp = 0; tp < 16; ++tp) {
        int t = th + tp * 2;
        if (t < NSTEP)
            tile[t][i] = Lall[(long)t * BB * VV + (long)b * VV + v0 + i];
    }
    __syncthreads();
    long obase = (long)b * VV * NSTEP + (long)v0 * NSTEP;
    for (int w = tid; w < 128 * NSTEP; w += 256)
        out[obase + w] = tile[w % NSTEP][w / NSTEP];
}

// ---- detect mask dtype and canonicalize ----
__global__ void mask_canon(const void* __restrict__ maskp, float* __restrict__ mA)
{
    __shared__ int ok;
    const unsigned char* bt = (const unsigned char*)maskp;
    int tid = threadIdx.x;
    if (tid == 0) ok = 1;
    __syncthreads();
    int bad = 0;
    for (int i = tid; i < BB * SS; i += 256) {
        unsigned char v = bt[i];
        if (v > 1) bad = 1;
        if ((i & (SS - 1)) != 0 && bt[i - 1] > v) bad = 1;
    }
    if (bad) atomicAnd(&ok, 0);
    __syncthreads();
    int packed = ok;
    const int* wi = (const int*)maskp;
    for (int i = tid; i < BB * SS; i += 256) {
        int m = packed ? (bt[i] != 0) : (wi[i] != 0);
        mA[i] = m ? -1.0e10f : 0.0f;
    }
}

__global__ void init_state(float* __restrict__ st, int* __restrict__ pred)
{
    int idx = blockIdx.x * 256 + threadIdx.x;
    st[idx] = 0.0f;
    if (idx < BB) pred[idx] = 1;
}

// sb[b,s] = enc[b,s,:] . v2 + s0
__global__ void sb_kernel(const float* __restrict__ enc, const float* __restrict__ v2,
                          const float* __restrict__ s0, float* __restrict__ sb)
{
    int bs = blockIdx.x * 256 + threadIdx.x;
    const float* kp = enc + (long)bs * DD;
    float a = 0;
    for (int d = 0; d < DD; d += 4) {
        float4 kv = *(const float4*)(kp + d);
        float4 bv = *(const float4*)(v2 + d);
        a += kv.x * bv.x + kv.y * bv.y + kv.z * bv.z + kv.w * bv.w;
    }
    sb[bs] = a + *s0;
}

extern "C" void kernel_launch(void* const* d_in, const int* in_sizes, int n_in,
                              void* d_out, int out_size, void* d_ws, size_t ws_size,
                              hipStream_t stream)
{
    const float* enc   = (const float*)d_in[0];
    const void*  maskp = d_in[1];
    const float* embt  = (const float*)d_in[2];
    const float* wq    = (const float*)d_in[3];
    const float* bq    = (const float*)d_in[4];
    const float* wk    = (const float*)d_in[5];
    const float* bk    = (const float*)d_in[6];
    const float* w_ih0 = (const float*)d_in[7];
    const float* w_hh0 = (const float*)d_in[8];
    const float* b_ih0 = (const float*)d_in[9];
    const float* b_hh0 = (const float*)d_in[10];
    const float* w_ih1 = (const float*)d_in[11];
    const float* w_hh1 = (const float*)d_in[12];
    const float* b_ih1 = (const float*)d_in[13];
    const float* b_hh1 = (const float*)d_in[14];
    const float* w_out = (const float*)d_in[15];
    const float* b_out = (const float*)d_in[16];

    float* out  = (float*)d_out;
    float* w    = (float*)d_ws;
    float* W2   = w + OFF_KEYS;
    float* v2   = W2 + 524288;
    float* b2v  = v2 + 1024;
    float* s0   = b2v + 512;
    float* K2b  = w + OFF_K2;
    float* sbb  = w + OFF_SB;
    float* mA   = w + OFF_MA;
    float* h0   = w + OFF_STATE;
    float* c0   = h0 + BB * HH;
    float* h1   = c0 + BB * HH;
    float* c1   = h1 + BB * HH;
    float* xb   = w + OFF_X;
    float* P    = w + OFF_P;
    int*   pred = (int*)(w + OFF_PRED);
    unsigned short* wh  = (unsigned short*)(w + OFF_WH);
    unsigned short* wl  = (unsigned short*)(w + OFF_WL);
    unsigned short* h1h = (unsigned short*)(w + OFF_H1H);
    unsigned short* h1l = (unsigned short*)(w + OFF_H1L);
    float* wlog = w + OFF_LOG;
    unsigned short* wc0h = (unsigned short*)(w + OFF_WC0H);
    unsigned short* wc0l = (unsigned short*)(w + OFF_WC0L);
    unsigned short* wc1h = (unsigned short*)(w + OFF_WC1H);
    unsigned short* wc1l = (unsigned short*)(w + OFF_WC1L);

    bool can_split = ws_size >= (size_t)TOTAL_FB * 4;
    bool buffered  = ws_size >= (size_t)TOTAL_BUF * 4;
    bool fused     = buffered && ws_size >= (size_t)TOTAL_MF * 4;

    mask_canon<<<1, 256, 0, stream>>>(maskp, mA);
    init_state<<<512, 256, 0, stream>>>(w + OFF_STATE, pred);

    prep_vecs<<<7, 256, 0, stream>>>(wk, wq, bq, bk, v2, b2v, s0);
    w2_gemm<<<dim3(8, 32), 256, 0, stream>>>(wk, wq, W2);
    gemm_kernel<0><<<dim3(4, 128), 256, 0, stream>>>(
        enc, W2, b2v, K2b, BB * SS, HH, DD, (long)HH, 1L, 0L);
    sb_kernel<<<32, 256, 0, stream>>>(enc, v2, s0, sbb);

    if (can_split)
        split_kernel<<<16000, 256, 0, stream>>>(w_out, wh, wl, VV * HH);

    if (fused) {
        cat_split<<<4096, 256, 0, stream>>>(w_ih0, XDIM, w_hh0, 2048, wc0h, wc0l,
                                            2048 * 2048);
        cat_split<<<2048, 256, 0, stream>>>(w_ih1, HH, w_hh1, 1024, wc1h, wc1l,
                                            2048 * 1024);
        zero_a<<<1536, 256, 0, stream>>>(w + OFF_A0);   // A0 + A1 (contiguous)
    }

    for (int t = 0; t < NSTEP; ++t) {
        int par = t & 1;
        unsigned short* a0h[2], * a0l[2], * a1h[2], * a1l[2];
        for (int pp = 0; pp < 2; ++pp) {
            a0h[pp] = (unsigned short*)(w + OFF_A0 + (long)pp * 131072);
            a0l[pp] = (unsigned short*)(w + OFF_A0 + (long)pp * 131072 + 65536);
            a1h[pp] = (unsigned short*)(w + OFF_A1 + (long)pp * 65536);
            a1l[pp] = (unsigned short*)(w + OFF_A1 + (long)pp * 65536 + 32768);
        }

        attn_embed<<<BB * 4, 256, 0, stream>>>(h1, K2b, sbb, mA, enc, embt, pred, xb,
                                               fused ? a0h[par] : nullptr,
                                               fused ? a0l[par] : nullptr);
        if (fused) {
            // layer0: A0[par]=[x|h0_{t-1}] -> h0_t into A0[par^1] h-slot + A1[par] x-slot
            gates_mfma<2048><<<32, 256, 0, stream>>>(
                a0h[par], a0l[par], wc0h, wc0l, b_ih0, b_hh0, c0, nullptr,
                a0h[par ^ 1], a0l[par ^ 1], 2048, 1536,
                a1h[par], a1l[par], 1024, 0);
            // layer1: A1[par]=[h0_t|h1_{t-1}] -> h1_t into A1[par^1] h-slot + h1h/h1l
            gates_mfma<1024><<<32, 256, 0, stream>>>(
                a1h[par], a1l[par], wc1h, wc1l, b_ih1, b_hh1, c1, h1,
                a1h[par ^ 1], a1l[par ^ 1], 1024, 512,
                h1h, h1l, 512, 0);
        } else {
            lstm_gates<<<dim3(16, 16), 256, 0, stream>>>(xb, XDIM, w_ih0, h0, HH, w_hh0, 12, P);
            lstm_act<<<128, 256, 0, stream>>>(P, 16, b_ih0, b_hh0, c0, h0, nullptr, nullptr);
            lstm_gates<<<dim3(16, 8), 256, 0, stream>>>(h0, HH, w_ih1, h1, HH, w_hh1, 4, P);
            lstm_act<<<128, 256, 0, stream>>>(P, 8, b_ih1, b_hh1, c1, h1,
                                              can_split ? h1h : nullptr, h1l);
        }

        float* Lt   = buffered ? (wlog + (long)t * BB * VV) : (out + t);
        long   ldm  = buffered ? (long)VV : (long)VV * NSTEP;
        long   ldn  = buffered ? 1L : (long)NSTEP;
        float* Cbase = buffered ? (wlog + (long)t * BB * VV) : out;
        long   coff = buffered ? 0L : (long)t;

        if (can_split) {
            logits_mfma<<<250, 256, 0, stream>>>(h1h, h1l, wh, wl, b_out,
                                                 Cbase, ldm, ldn, coff);
        } else {
            gemm_kernel<1><<<dim3(250, 1), 256, 0, stream>>>(
                h1, w_out, b_out, Cbase, BB, VV, HH, ldm, ldn, coff);
        }
        argmax_kernel<<<BB, 256, 0, stream>>>(Lt, buffered ? (long)VV : (long)VV * NSTEP,
                                              ldn, pred);
    }
    if (buffered)
        transpose_out<<<dim3(BB, VV / 128), 256, 0, stream>>>(wlog, out);
}

// Round 4
// 4502.970 us; speedup vs baseline: 1.6638x; 1.6638x over previous
//
#include <hip/hip_runtime.h>
#include <math.h>

#define BB 64
#define SS 128
#define DD 1024
#define HH 512
#define EE 512
#define VV 32000
#define NSTEP 31
#define G4 2048        // 4*H
#define XDIM 1536      // E + D_enc

// ---------------- workspace layout (in floats) ----------------
#define OFF_KEYS   0L                                  // W2/v2/b2/s0
#define OFF_K2     8388608L
#define OFF_SB     12582912L
#define OFF_MA     12591104L
#define OFF_STATE  12599296L                           // h0,c0,h1,c1 (131072)
#define OFF_X      12730368L
#define OFF_P      12828672L
#define OFF_PRED   14925824L
#define OFF_WH     14925888L
#define OFF_WL     23117888L
#define OFF_H1H    31309888L
#define OFF_H1L    31326272L
#define OFF_LOG    31342656L                           // 63488000
#define TOTAL_BUF  94830656L
#define TOTAL_FB   31342656L
// ---- fused-MFMA LSTM extras (beyond TOTAL_BUF) ----
#define OFF_WC0H   94830656L                           // 2048x2048 bf16 hi (2097152 fl)
#define OFF_WC0L   96927808L
#define OFF_WC1H   99024960L                           // 2048x1024 bf16 hi (1048576 fl)
#define OFF_WC1L   100073536L
#define OFF_A0     101122112L                          // 2 par x (hi 65536 + lo 65536) fl
#define OFF_A1     101384256L                          // 2 par x (hi 32768 + lo 32768) fl
#define TOTAL_MF   101515328L

typedef __attribute__((ext_vector_type(8))) short short8;
typedef __attribute__((ext_vector_type(4))) float float4v;

__device__ __forceinline__ unsigned short bf16_rne(float v)
{
    unsigned u = __float_as_uint(v);
    unsigned r = (u + 0x7FFF + ((u >> 16) & 1)) >> 16;
    return (unsigned short)r;
}

// =====================================================================
// Generic fp32 GEMM (K2 gemm + logits fallback)
// =====================================================================
template<int BT>
__global__ __launch_bounds__(256)
void gemm_kernel(const float* __restrict__ A, const float* __restrict__ Bm,
                 const float* __restrict__ bias, float* __restrict__ C,
                 int M, int N, int K, long ldm, long ldn, long coff)
{
    __shared__ float As[32][68];
    __shared__ float Bs[32][132];
    int tid = threadIdx.x;
    int tx = tid & 15, ty = tid >> 4;
    int m0 = blockIdx.y * 64, n0 = blockIdx.x * 128;

    float acc[4][8];
#pragma unroll
    for (int i = 0; i < 4; ++i)
#pragma unroll
        for (int j = 0; j < 8; ++j) acc[i][j] = 0.0f;

    int ar = tid >> 3;          // 0..31
    int ac = (tid & 7) * 4;     // 0,4,...,28

    for (int kk = 0; kk < K; kk += 32) {
#pragma unroll
        for (int p = 0; p < 2; ++p) {
            int r = ar + p * 32;
            float4 v = *(const float4*)(A + (long)(m0 + r) * K + kk + ac);
            As[ac + 0][r] = v.x; As[ac + 1][r] = v.y;
            As[ac + 2][r] = v.z; As[ac + 3][r] = v.w;
        }
        if (BT) {
#pragma unroll
            for (int p = 0; p < 4; ++p) {
                int n = ar + p * 32;
                float4 v = *(const float4*)(Bm + (long)(n0 + n) * K + kk + ac);
                Bs[ac + 0][n] = v.x; Bs[ac + 1][n] = v.y;
                Bs[ac + 2][n] = v.z; Bs[ac + 3][n] = v.w;
            }
        } else {
            int bn = (tid & 31) * 4;
            int bk = tid >> 5;
#pragma unroll
            for (int p = 0; p < 4; ++p) {
                int k = bk + p * 8;
                float4 v = *(const float4*)(Bm + (long)(kk + k) * N + n0 + bn);
                *(float4*)&Bs[k][bn] = v;
            }
        }
        __syncthreads();
#pragma unroll
        for (int k = 0; k < 32; ++k) {
            float4 a  = *(const float4*)&As[k][ty * 4];
            float4 b0 = *(const float4*)&Bs[k][tx * 8];
            float4 b1 = *(const float4*)&Bs[k][tx * 8 + 4];
            float av[4] = {a.x, a.y, a.z, a.w};
            float bv[8] = {b0.x, b0.y, b0.z, b0.w, b1.x, b1.y, b1.z, b1.w};
#pragma unroll
            for (int im = 0; im < 4; ++im)
#pragma unroll
                for (int in = 0; in < 8; ++in)
                    acc[im][in] = fmaf(av[im], bv[in], acc[im][in]);
        }
        __syncthreads();
    }

#pragma unroll
    for (int im = 0; im < 4; ++im) {
        int m = m0 + ty * 4 + im;
#pragma unroll
        for (int in = 0; in < 8; ++in) {
            int n = n0 + tx * 8 + in;
            float r = acc[im][in];
            if (bias) r += bias[n];
            C[coff + (long)m * ldm + (long)n * ldn] = r;
        }
    }
}

// =====================================================================
// W2 = wk^T @ wq   (TN gemm)
// =====================================================================
__global__ __launch_bounds__(256)
void w2_gemm(const float* __restrict__ wk, const float* __restrict__ wq,
             float* __restrict__ W2)
{
    __shared__ float As[32][36];
    __shared__ float Bs[32][68];
    int tid = threadIdx.x;
    int d0 = blockIdx.y * 32, h0 = blockIdx.x * 64;
    int tx = tid & 15, ty = tid >> 4;

    float acc[2][4];
#pragma unroll
    for (int i = 0; i < 2; ++i)
#pragma unroll
        for (int j = 0; j < 4; ++j) acc[i][j] = 0.0f;

    int le = tid >> 3;
    int ld = (tid & 7) * 4;
    int lh = (tid & 7) * 8;

    for (int e0 = 0; e0 < DD; e0 += 32) {
        float4 va = *(const float4*)(wk + (long)(e0 + le) * DD + d0 + ld);
        *(float4*)&As[le][ld] = va;
        float4 vb0 = *(const float4*)(wq + (long)(e0 + le) * HH + h0 + lh);
        float4 vb1 = *(const float4*)(wq + (long)(e0 + le) * HH + h0 + lh + 4);
        *(float4*)&Bs[le][lh] = vb0;
        *(float4*)&Bs[le][lh + 4] = vb1;
        __syncthreads();
#pragma unroll
        for (int k = 0; k < 32; ++k) {
            float a0 = As[k][ty * 2];
            float a1 = As[k][ty * 2 + 1];
            float4 b = *(const float4*)&Bs[k][tx * 4];
            float bv[4] = {b.x, b.y, b.z, b.w};
#pragma unroll
            for (int j = 0; j < 4; ++j) {
                acc[0][j] = fmaf(a0, bv[j], acc[0][j]);
                acc[1][j] = fmaf(a1, bv[j], acc[1][j]);
            }
        }
        __syncthreads();
    }
#pragma unroll
    for (int i = 0; i < 2; ++i)
#pragma unroll
        for (int j = 0; j < 4; ++j)
            W2[(long)(d0 + ty * 2 + i) * HH + h0 + tx * 4 + j] = acc[i][j];
}

// v2[d] = wk^T @ bq ; b2[h] = bk @ wq ; s0 = bk . bq
__global__ __launch_bounds__(256)
void prep_vecs(const float* __restrict__ wk, const float* __restrict__ wq,
               const float* __restrict__ bq, const float* __restrict__ bk,
               float* __restrict__ v2, float* __restrict__ b2,
               float* __restrict__ s0)
{
    int idx = blockIdx.x * 256 + threadIdx.x;
    if (idx < DD) {
        float a = 0;
        for (int e = 0; e < DD; ++e) a += wk[(long)e * DD + idx] * bq[e];
        v2[idx] = a;
    } else if (idx < DD + HH) {
        int h = idx - DD;
        float a = 0;
        for (int e = 0; e < DD; ++e) a += bk[e] * wq[(long)e * HH + h];
        b2[h] = a;
    } else if (idx == DD + HH) {
        float a = 0;
        for (int e = 0; e < DD; ++e) a += bk[e] * bq[e];
        *s0 = a;
    }
}

// ---- bf16 hi/lo split of an fp32 array ----
__global__ __launch_bounds__(256)
void split_kernel(const float* __restrict__ x, unsigned short* __restrict__ hi,
                  unsigned short* __restrict__ lo, int n)
{
    int i = (blockIdx.x * 256 + threadIdx.x) * 4;
    if (i >= n) return;
    float4 v = *(const float4*)(x + i);
    float vv[4] = {v.x, v.y, v.z, v.w};
    unsigned hpack[2], lpack[2];
#pragma unroll
    for (int p = 0; p < 2; ++p) {
        unsigned short h0 = bf16_rne(vv[2 * p]);
        unsigned short h1 = bf16_rne(vv[2 * p + 1]);
        float f0 = __uint_as_float((unsigned)h0 << 16);
        float f1 = __uint_as_float((unsigned)h1 << 16);
        unsigned short l0 = bf16_rne(vv[2 * p] - f0);
        unsigned short l1 = bf16_rne(vv[2 * p + 1] - f1);
        hpack[p] = (unsigned)h0 | ((unsigned)h1 << 16);
        lpack[p] = (unsigned)l0 | ((unsigned)l1 << 16);
    }
    *(uint2*)(hi + i) = make_uint2(hpack[0], hpack[1]);
    *(uint2*)(lo + i) = make_uint2(lpack[0], lpack[1]);
}

// ---- gate-interleaved concat + bf16 hi/lo split ----
// Interleaved row r (0..2047): gate g = r&3, h-col j = r>>2.
// Source row g*512+j of [s1 | s2] (K1 + (KK-K1) cols).
__global__ __launch_bounds__(256)
void cat_split_ilv(const float* __restrict__ s1, int K1, const float* __restrict__ s2,
                   int KK, unsigned short* __restrict__ hi, unsigned short* __restrict__ lo,
                   int total)
{
    int e = (blockIdx.x * 256 + threadIdx.x) * 4;
    if (e >= total) return;
    int r = e / KK, k = e - r * KK;
    int g = r & 3, j = r >> 2;
    int srow = g * 512 + j;
    const float* src = (k < K1) ? (s1 + (long)srow * K1 + k)
                                : (s2 + (long)srow * (KK - K1) + (k - K1));
    float4 v = *(const float4*)src;
    float vv[4] = {v.x, v.y, v.z, v.w};
    unsigned hpack[2], lpack[2];
#pragma unroll
    for (int p = 0; p < 2; ++p) {
        unsigned short h0 = bf16_rne(vv[2 * p]);
        unsigned short h1 = bf16_rne(vv[2 * p + 1]);
        float f0 = __uint_as_float((unsigned)h0 << 16);
        float f1 = __uint_as_float((unsigned)h1 << 16);
        unsigned short l0 = bf16_rne(vv[2 * p] - f0);
        unsigned short l1 = bf16_rne(vv[2 * p + 1] - f1);
        hpack[p] = (unsigned)h0 | ((unsigned)h1 << 16);
        lpack[p] = (unsigned)l0 | ((unsigned)l1 << 16);
    }
    *(uint2*)(hi + e) = make_uint2(hpack[0], hpack[1]);
    *(uint2*)(lo + e) = make_uint2(lpack[0], lpack[1]);
}

__global__ __launch_bounds__(256)
void zero_a(float* __restrict__ p)
{
    p[blockIdx.x * 256 + threadIdx.x] = 0.0f;
}

// =====================================================================
// Logits GEMM via bf16-split MFMA (3-term): C(64,32000) = h1 @ w_out^T
// =====================================================================
__global__ __launch_bounds__(256)
void logits_mfma(const unsigned short* __restrict__ Ah, const unsigned short* __restrict__ Al,
                 const unsigned short* __restrict__ Bh, const unsigned short* __restrict__ Bl,
                 const float* __restrict__ bias, float* __restrict__ C,
                 long ldm, long ldn, long coff)
{
    int tid = threadIdx.x;
    int wid = tid >> 6, lane = tid & 63;
    int ln = lane & 15, q = lane >> 4;
    int nb = blockIdx.x * 128 + wid * 32;

    float4v acc[4][2];
#pragma unroll
    for (int mf = 0; mf < 4; ++mf)
#pragma unroll
        for (int nf = 0; nf < 2; ++nf)
            acc[mf][nf] = (float4v){0.f, 0.f, 0.f, 0.f};

    const int kb = q * 8;
#pragma unroll 2
    for (int k0 = 0; k0 < 512; k0 += 32) {
        long ko = k0 + kb;
        short8 a_h[4], a_l[4], b_h[2], b_l[2];
#pragma unroll
        for (int nf = 0; nf < 2; ++nf) {
            long row = (long)(nb + nf * 16 + ln) * 512 + ko;
            b_h[nf] = *(const short8*)(Bh + row);
            b_l[nf] = *(const short8*)(Bl + row);
        }
#pragma unroll
        for (int mf = 0; mf < 4; ++mf) {
            long row = (long)(mf * 16 + ln) * 512 + ko;
            a_h[mf] = *(const short8*)(Ah + row);
            a_l[mf] = *(const short8*)(Al + row);
        }
#pragma unroll
        for (int mf = 0; mf < 4; ++mf)
#pragma unroll
            for (int nf = 0; nf < 2; ++nf) {
                acc[mf][nf] = __builtin_amdgcn_mfma_f32_16x16x32_bf16(a_h[mf], b_h[nf], acc[mf][nf], 0, 0, 0);
                acc[mf][nf] = __builtin_amdgcn_mfma_f32_16x16x32_bf16(a_l[mf], b_h[nf], acc[mf][nf], 0, 0, 0);
                acc[mf][nf] = __builtin_amdgcn_mfma_f32_16x16x32_bf16(a_h[mf], b_l[nf], acc[mf][nf], 0, 0, 0);
            }
    }

#pragma unroll
    for (int nf = 0; nf < 2; ++nf) {
        int n = nb + nf * 16 + ln;
        float bo = bias[n];
#pragma unroll
        for (int mf = 0; mf < 4; ++mf)
#pragma unroll
            for (int r = 0; r < 4; ++r) {
                int m = mf * 16 + q * 4 + r;
                C[coff + (long)m * ldm + (long)n * ldn] = acc[mf][nf][r] + bo;
            }
    }
}

// =====================================================================
// Fused LSTM layer v2: gate-interleaved W, 128 blocks x 8 waves,
// 8-way K-split + LDS reduce, wave-local epilogue.
// Block nf (0..127): interleaved W rows [nf*16, nf*16+16) = h-cols
// [nf*4,nf*4+4) x 4 gates. Wave kw: K-range [kw*KK/8, (kw+1)*KK/8).
// =====================================================================
template<int KK>
__global__ __launch_bounds__(512)
void gates_mfma2(const unsigned short* __restrict__ Ah, const unsigned short* __restrict__ Al,
                 const unsigned short* __restrict__ Wh, const unsigned short* __restrict__ Wl,
                 const float* __restrict__ b_ih, const float* __restrict__ b_hh,
                 float* __restrict__ c, float* __restrict__ hout,
                 unsigned short* __restrict__ d1h, unsigned short* __restrict__ d1l,
                 int d1ld, int d1off,
                 unsigned short* __restrict__ d2h, unsigned short* __restrict__ d2l,
                 int d2ld, int d2off)
{
    __shared__ float gacc[8][64][17];
    int tid = threadIdx.x;
    int kw = tid >> 6, lane = tid & 63;
    int ln = lane & 15, q = lane >> 4;
    int nf = blockIdx.x;
    const int KS = KK / 8;            // per-wave K range
    const int kbase = kw * KS;
    long wrow = (long)(nf * 16 + ln) * KK;

    float4v acc[4];
#pragma unroll
    for (int mf = 0; mf < 4; ++mf) acc[mf] = (float4v){0.f, 0.f, 0.f, 0.f};

    const int kb = q * 8;
#pragma unroll 2
    for (int k0 = 0; k0 < KS; k0 += 32) {
        long ko = kbase + k0 + kb;
        short8 b_h = *(const short8*)(Wh + wrow + ko);
        short8 b_l = *(const short8*)(Wl + wrow + ko);
        short8 a_h[4], a_l[4];
#pragma unroll
        for (int mf = 0; mf < 4; ++mf) {
            long arow = (long)(mf * 16 + ln) * KK + ko;
            a_h[mf] = *(const short8*)(Ah + arow);
            a_l[mf] = *(const short8*)(Al + arow);
        }
#pragma unroll
        for (int mf = 0; mf < 4; ++mf) {
            acc[mf] = __builtin_amdgcn_mfma_f32_16x16x32_bf16(a_h[mf], b_h, acc[mf], 0, 0, 0);
            acc[mf] = __builtin_amdgcn_mfma_f32_16x16x32_bf16(a_l[mf], b_h, acc[mf], 0, 0, 0);
            acc[mf] = __builtin_amdgcn_mfma_f32_16x16x32_bf16(a_h[mf], b_l, acc[mf], 0, 0, 0);
            acc[mf] = __builtin_amdgcn_mfma_f32_16x16x32_bf16(a_l[mf], b_l, acc[mf], 0, 0, 0);
        }
    }

#pragma unroll
    for (int mf = 0; mf < 4; ++mf)
#pragma unroll
        for (int r = 0; r < 4; ++r)
            gacc[kw][mf * 16 + q * 4 + r][ln] = acc[mf][r];
    __syncthreads();

    // epilogue: thread t<256 -> batch m = t>>2, h-col jj = t&3 (all 4 gates local)
    if (tid < 256) {
        int m = tid >> 2, jj = tid & 3;
        int J = nf * 4 + jj;                   // global h-col 0..511
        float gv[4];
#pragma unroll
        for (int g = 0; g < 4; ++g) {
            float v = 0;
#pragma unroll
            for (int w = 0; w < 8; ++w) v += gacc[w][m][jj * 4 + g];
            gv[g] = v + b_ih[g * HH + J] + b_hh[g * HH + J];
        }
        float i_ = 1.0f / (1.0f + expf(-gv[0]));
        float f_ = 1.0f / (1.0f + expf(-gv[1]));
        float g_ = tanhf(gv[2]);
        float o_ = 1.0f / (1.0f + expf(-gv[3]));
        int ci = m * HH + J;
        float cn = f_ * c[ci] + i_ * g_;
        c[ci] = cn;
        float hv = o_ * tanhf(cn);
        if (hout) hout[ci] = hv;
        unsigned short hb = bf16_rne(hv);
        float hf = __uint_as_float((unsigned)hb << 16);
        unsigned short lb = bf16_rne(hv - hf);
        d1h[m * d1ld + d1off + J] = hb;
        d1l[m * d1ld + d1off + J] = lb;
        if (d2h) {
            d2h[m * d2ld + d2off + J] = hb;
            d2l[m * d2ld + d2off + J] = lb;
        }
    }
}

// =====================================================================
// LSTM gates split-K GEMM (fallback path)
// =====================================================================
__global__ __launch_bounds__(256)
void lstm_gates(const float* __restrict__ A1, int K1, const float* __restrict__ B1,
                const float* __restrict__ A2, int K2c, const float* __restrict__ B2,
                int z1, float* __restrict__ P)
{
    __shared__ float As[32][68];
    __shared__ float Bs[32][132];
    int tid = threadIdx.x;
    int tx = tid & 15, ty = tid >> 4;
    int n0 = blockIdx.x * 128;
    int z = blockIdx.y;

    const float* A; const float* Bw; int kb, lda;
    if (z < z1) { A = A1; Bw = B1; kb = z * 128;        lda = K1; }
    else        { A = A2; Bw = B2; kb = (z - z1) * 128; lda = K2c; }

    float acc[4][8];
#pragma unroll
    for (int i = 0; i < 4; ++i)
#pragma unroll
        for (int j = 0; j < 8; ++j) acc[i][j] = 0.0f;

    int ar = tid >> 3;
    int ac = (tid & 7) * 4;

    for (int kk = kb; kk < kb + 128; kk += 32) {
#pragma unroll
        for (int p = 0; p < 2; ++p) {
            int r = ar + p * 32;
            float4 v = *(const float4*)(A + (long)r * lda + kk + ac);
            As[ac + 0][r] = v.x; As[ac + 1][r] = v.y;
            As[ac + 2][r] = v.z; As[ac + 3][r] = v.w;
        }
#pragma unroll
        for (int p = 0; p < 4; ++p) {
            int n = ar + p * 32;
            float4 v = *(const float4*)(Bw + (long)(n0 + n) * lda + kk + ac);
            Bs[ac + 0][n] = v.x; Bs[ac + 1][n] = v.y;
            Bs[ac + 2][n] = v.z; Bs[ac + 3][n] = v.w;
        }
        __syncthreads();
#pragma unroll
        for (int k = 0; k < 32; ++k) {
            float4 a  = *(const float4*)&As[k][ty * 4];
            float4 b0 = *(const float4*)&Bs[k][tx * 8];
            float4 b1 = *(const float4*)&Bs[k][tx * 8 + 4];
            float av[4] = {a.x, a.y, a.z, a.w};
            float bv[8] = {b0.x, b0.y, b0.z, b0.w, b1.x, b1.y, b1.z, b1.w};
#pragma unroll
            for (int im = 0; im < 4; ++im)
#pragma unroll
                for (int in = 0; in < 8; ++in)
                    acc[im][in] = fmaf(av[im], bv[in], acc[im][in]);
        }
        __syncthreads();
    }

    float* Pp = P + (long)z * (BB * (long)G4);
#pragma unroll
    for (int im = 0; im < 4; ++im) {
        int m = ty * 4 + im;
#pragma unroll
        for (int in = 0; in < 8; ++in)
            Pp[(long)m * G4 + n0 + tx * 8 + in] = acc[im][in];
    }
}

// ---- fallback act ----
__global__ __launch_bounds__(256)
void lstm_act(const float* __restrict__ P, int z,
              const float* __restrict__ b_ih, const float* __restrict__ b_hh,
              float* __restrict__ c, float* __restrict__ h,
              unsigned short* __restrict__ hh, unsigned short* __restrict__ hl)
{
    int idx = blockIdx.x * 256 + threadIdx.x;
    int b = idx >> 9, j = idx & 511;
    float gi = 0, gf = 0, gg = 0, go = 0;
    for (int zi = 0; zi < z; ++zi) {
        const float* p = P + (long)zi * (BB * (long)G4) + (long)b * G4 + j;
        gi += p[0]; gf += p[HH]; gg += p[2 * HH]; go += p[3 * HH];
    }
    gi += b_ih[j] + b_hh[j];
    gf += b_ih[HH + j] + b_hh[HH + j];
    gg += b_ih[2 * HH + j] + b_hh[2 * HH + j];
    go += b_ih[3 * HH + j] + b_hh[3 * HH + j];
    float i_ = 1.0f / (1.0f + expf(-gi));
    float f_ = 1.0f / (1.0f + expf(-gf));
    float g_ = tanhf(gg);
    float o_ = 1.0f / (1.0f + expf(-go));
    float cn = f_ * c[idx] + i_ * g_;
    c[idx] = cn;
    float hv = o_ * tanhf(cn);
    h[idx] = hv;
    if (hh) {
        unsigned short hb = bf16_rne(hv);
        float hf = __uint_as_float((unsigned)hb << 16);
        hh[idx] = hb;
        hl[idx] = bf16_rne(hv - hf);
    }
}

// ---- fused: embedding gather + attention, 4-way d-chunked ctx ----
__global__ __launch_bounds__(256)
void attn_embed(const float* __restrict__ h1, const float* __restrict__ K2,
                const float* __restrict__ sb, const float* __restrict__ mA,
                const float* __restrict__ enc, const float* __restrict__ emb,
                const int* __restrict__ pred, float* __restrict__ x,
                unsigned short* __restrict__ a0h, unsigned short* __restrict__ a0l)
{
    __shared__ float shH[512];
    __shared__ float shP[256];
    __shared__ float shS[128];
    __shared__ float shR[64];
    int blk = blockIdx.x;
    int b = blk >> 2, ch = blk & 3;
    int tid = threadIdx.x;

    shH[tid]       = h1[b * HH + tid];
    shH[tid + 256] = h1[b * HH + 256 + tid];
    float* xr = x + (long)b * XDIM;
    if (ch == 0) {
        const float* et = emb + (long)pred[b] * EE;
        float v0 = et[tid], v1 = et[tid + 256];
        xr[tid]       = v0;
        xr[tid + 256] = v1;
        if (a0h) {
            unsigned short h0b = bf16_rne(v0);
            unsigned short h1b = bf16_rne(v1);
            a0h[b * 2048 + tid]       = h0b;
            a0h[b * 2048 + tid + 256] = h1b;
            a0l[b * 2048 + tid]       = bf16_rne(v0 - __uint_as_float((unsigned)h0b << 16));
            a0l[b * 2048 + tid + 256] = bf16_rne(v1 - __uint_as_float((unsigned)h1b << 16));
        }
    }
    __syncthreads();

    {
        int s = tid >> 1, hf = tid & 1;
        const float* kp = K2 + ((long)(b * SS + s)) * HH + hf * 256;
        const float* hp = shH + hf * 256;
        float a = 0;
        for (int j = 0; j < 256; j += 4) {
            float4 v = *(const float4*)(kp + j);
            a += hp[j] * v.x + hp[j + 1] * v.y + hp[j + 2] * v.z + hp[j + 3] * v.w;
        }
        shP[tid] = a;
    }
    __syncthreads();
    if (tid < 128) {
        float sc = (shP[2 * tid] + shP[2 * tid + 1] + sb[b * SS + tid]) * 0.03125f
                   + mA[b * SS + tid];
        shS[tid] = sc;
    }
    __syncthreads();
    if (tid < 64) shR[tid] = fmaxf(shS[tid], shS[tid + 64]);
    __syncthreads();
    if (tid < 32) shR[tid] = fmaxf(shR[tid], shR[tid + 32]);
    __syncthreads();
    if (tid < 16) shR[tid] = fmaxf(shR[tid], shR[tid + 16]);
    __syncthreads();
    if (tid < 8)  shR[tid] = fmaxf(shR[tid], shR[tid + 8]);
    __syncthreads();
    if (tid < 4)  shR[tid] = fmaxf(shR[tid], shR[tid + 4]);
    __syncthreads();
    if (tid < 2)  shR[tid] = fmaxf(shR[tid], shR[tid + 2]);
    __syncthreads();
    if (tid == 0) shR[0] = fmaxf(shR[0], shR[1]);
    __syncthreads();
    float mx = shR[0];
    __syncthreads();
    if (tid < 128) shS[tid] = expf(shS[tid] - mx);
    __syncthreads();
    if (tid < 64) shR[tid] = shS[tid] + shS[tid + 64];
    __syncthreads();
    if (tid < 32) shR[tid] += shR[tid + 32];
    __syncthreads();
    if (tid < 16) shR[tid] += shR[tid + 16];
    __syncthreads();
    if (tid < 8)  shR[tid] += shR[tid + 8];
    __syncthreads();
    if (tid < 4)  shR[tid] += shR[tid + 4];
    __syncthreads();
    if (tid < 2)  shR[tid] += shR[tid + 2];
    __syncthreads();
    if (tid == 0) shR[0] += shR[1];
    __syncthreads();
    float inv = 1.0f / shR[0];
    if (tid < 128) shS[tid] *= inv;
    __syncthreads();

    const float* ep = enc + (long)b * SS * DD + ch * 256 + tid;
    float a = 0;
#pragma unroll 4
    for (int s = 0; s < SS; ++s)
        a += shS[s] * ep[(long)s * DD];
    int col = EE + ch * 256 + tid;
    xr[col] = a;
    if (a0h) {
        unsigned short hb = bf16_rne(a);
        a0h[b * 2048 + col] = hb;
        a0l[b * 2048 + col] = bf16_rne(a - __uint_as_float((unsigned)hb << 16));
    }
}

// ---- greedy argmax (first max) ----
__global__ __launch_bounds__(256)
void argmax_kernel(const float* __restrict__ L, long rowStride, long vStride,
                   int* __restrict__ pred)
{
    __shared__ float shV[256];
    __shared__ int   shI[256];
    int b = blockIdx.x, tid = threadIdx.x;
    const float* p = L + (long)b * rowStride;
    float best = -INFINITY; int bi = 0;
    for (int v = tid; v < VV; v += 256) {
        float val = p[(long)v * vStride];
        if (val > best) { best = val; bi = v; }
    }
    shV[tid] = best; shI[tid] = bi;
    __syncthreads();
    for (int o = 128; o > 0; o >>= 1) {
        if (tid < o) {
            float ov = shV[tid + o]; int oi = shI[tid + o];
            if (ov > shV[tid] || (ov == shV[tid] && oi < shI[tid])) {
                shV[tid] = ov; shI[tid] = oi;
            }
        }
        __syncthreads();
    }
    if (tid == 0) pred[b] = shI[0];
}

// ---- (T,B,V) -> (B,V,T) transpose via LDS ----
__global__ __launch_bounds__(256)
void transpose_out(const float* __restrict__ Lall, float* __restrict__ out)
{
    __shared__ float tile[NSTEP][129];
    int b = blockIdx.x, v0 = blockIdx.y * 128, tid = threadIdx.x;
    int i = tid & 127, th = tid >> 7;
    for (int tp = 0; tp < 16; ++tp) {
        int t = th + tp * 2;
        if (t < NSTEP)
            tile[t][i] = Lall[(long)t * BB * VV + (long)b * VV + v0 + i];
    }
    __syncthreads();
    long obase = (long)b * VV * NSTEP + (long)v0 * NSTEP;
    for (int w = tid; w < 128 * NSTEP; w += 256)
        out[obase + w] = tile[w % NSTEP][w / NSTEP];
}

// ---- detect mask dtype and canonicalize ----
__global__ void mask_canon(const void* __restrict__ maskp, float* __restrict__ mA)
{
    __shared__ int ok;
    const unsigned char* bt = (const unsigned char*)maskp;
    int tid = threadIdx.x;
    if (tid == 0) ok = 1;
    __syncthreads();
    int bad = 0;
    for (int i = tid; i < BB * SS; i += 256) {
        unsigned char v = bt[i];
        if (v > 1) bad = 1;
        if ((i & (SS - 1)) != 0 && bt[i - 1] > v) bad = 1;
    }
    if (bad) atomicAnd(&ok, 0);
    __syncthreads();
    int packed = ok;
    const int* wi = (const int*)maskp;
    for (int i = tid; i < BB * SS; i += 256) {
        int m = packed ? (bt[i] != 0) : (wi[i] != 0);
        mA[i] = m ? -1.0e10f : 0.0f;
    }
}

__global__ void init_state(float* __restrict__ st, int* __restrict__ pred)
{
    int idx = blockIdx.x * 256 + threadIdx.x;
    st[idx] = 0.0f;
    if (idx < BB) pred[idx] = 1;
}

// sb[b,s] = enc[b,s,:] . v2 + s0
__global__ void sb_kernel(const float* __restrict__ enc, const float* __restrict__ v2,
                          const float* __restrict__ s0, float* __restrict__ sb)
{
    int bs = blockIdx.x * 256 + threadIdx.x;
    const float* kp = enc + (long)bs * DD;
    float a = 0;
    for (int d = 0; d < DD; d += 4) {
        float4 kv = *(const float4*)(kp + d);
        float4 bv = *(const float4*)(v2 + d);
        a += kv.x * bv.x + kv.y * bv.y + kv.z * bv.z + kv.w * bv.w;
    }
    sb[bs] = a + *s0;
}

extern "C" void kernel_launch(void* const* d_in, const int* in_sizes, int n_in,
                              void* d_out, int out_size, void* d_ws, size_t ws_size,
                              hipStream_t stream)
{
    const float* enc   = (const float*)d_in[0];
    const void*  maskp = d_in[1];
    const float* embt  = (const float*)d_in[2];
    const float* wq    = (const float*)d_in[3];
    const float* bq    = (const float*)d_in[4];
    const float* wk    = (const float*)d_in[5];
    const float* bk    = (const float*)d_in[6];
    const float* w_ih0 = (const float*)d_in[7];
    const float* w_hh0 = (const float*)d_in[8];
    const float* b_ih0 = (const float*)d_in[9];
    const float* b_hh0 = (const float*)d_in[10];
    const float* w_ih1 = (const float*)d_in[11];
    const float* w_hh1 = (const float*)d_in[12];
    const float* b_ih1 = (const float*)d_in[13];
    const float* b_hh1 = (const float*)d_in[14];
    const float* w_out = (const float*)d_in[15];
    const float* b_out = (const float*)d_in[16];

    float* out  = (float*)d_out;
    float* w    = (float*)d_ws;
    float* W2   = w + OFF_KEYS;
    float* v2   = W2 + 524288;
    float* b2v  = v2 + 1024;
    float* s0   = b2v + 512;
    float* K2b  = w + OFF_K2;
    float* sbb  = w + OFF_SB;
    float* mA   = w + OFF_MA;
    float* h0   = w + OFF_STATE;
    float* c0   = h0 + BB * HH;
    float* h1   = c0 + BB * HH;
    float* c1   = h1 + BB * HH;
    float* xb   = w + OFF_X;
    float* P    = w + OFF_P;
    int*   pred = (int*)(w + OFF_PRED);
    unsigned short* wh  = (unsigned short*)(w + OFF_WH);
    unsigned short* wl  = (unsigned short*)(w + OFF_WL);
    unsigned short* h1h = (unsigned short*)(w + OFF_H1H);
    unsigned short* h1l = (unsigned short*)(w + OFF_H1L);
    float* wlog = w + OFF_LOG;
    unsigned short* wc0h = (unsigned short*)(w + OFF_WC0H);
    unsigned short* wc0l = (unsigned short*)(w + OFF_WC0L);
    unsigned short* wc1h = (unsigned short*)(w + OFF_WC1H);
    unsigned short* wc1l = (unsigned short*)(w + OFF_WC1L);

    bool can_split = ws_size >= (size_t)TOTAL_FB * 4;
    bool buffered  = ws_size >= (size_t)TOTAL_BUF * 4;
    bool fused     = buffered && ws_size >= (size_t)TOTAL_MF * 4;

    mask_canon<<<1, 256, 0, stream>>>(maskp, mA);
    init_state<<<512, 256, 0, stream>>>(w + OFF_STATE, pred);

    prep_vecs<<<7, 256, 0, stream>>>(wk, wq, bq, bk, v2, b2v, s0);
    w2_gemm<<<dim3(8, 32), 256, 0, stream>>>(wk, wq, W2);
    gemm_kernel<0><<<dim3(4, 128), 256, 0, stream>>>(
        enc, W2, b2v, K2b, BB * SS, HH, DD, (long)HH, 1L, 0L);
    sb_kernel<<<32, 256, 0, stream>>>(enc, v2, s0, sbb);

    if (can_split)
        split_kernel<<<16000, 256, 0, stream>>>(w_out, wh, wl, VV * HH);

    if (fused) {
        cat_split_ilv<<<4096, 256, 0, stream>>>(w_ih0, XDIM, w_hh0, 2048, wc0h, wc0l,
                                                2048 * 2048);
        cat_split_ilv<<<2048, 256, 0, stream>>>(w_ih1, HH, w_hh1, 1024, wc1h, wc1l,
                                                2048 * 1024);
        zero_a<<<1536, 256, 0, stream>>>(w + OFF_A0);   // A0 + A1 (contiguous)
    }

    for (int t = 0; t < NSTEP; ++t) {
        int par = t & 1;
        unsigned short* a0h[2], * a0l[2], * a1h[2], * a1l[2];
        for (int pp = 0; pp < 2; ++pp) {
            a0h[pp] = (unsigned short*)(w + OFF_A0 + (long)pp * 131072);
            a0l[pp] = (unsigned short*)(w + OFF_A0 + (long)pp * 131072 + 65536);
            a1h[pp] = (unsigned short*)(w + OFF_A1 + (long)pp * 65536);
            a1l[pp] = (unsigned short*)(w + OFF_A1 + (long)pp * 65536 + 32768);
        }

        attn_embed<<<BB * 4, 256, 0, stream>>>(h1, K2b, sbb, mA, enc, embt, pred, xb,
                                               fused ? a0h[par] : nullptr,
                                               fused ? a0l[par] : nullptr);
        if (fused) {
            // layer0: A0[par]=[x|h0_{t-1}] -> h0_t into A0[par^1] h-slot + A1[par] x-slot
            gates_mfma2<2048><<<128, 512, 0, stream>>>(
                a0h[par], a0l[par], wc0h, wc0l, b_ih0, b_hh0, c0, nullptr,
                a0h[par ^ 1], a0l[par ^ 1], 2048, 1536,
                a1h[par], a1l[par], 1024, 0);
            // layer1: A1[par]=[h0_t|h1_{t-1}] -> h1_t into A1[par^1] h-slot + h1h/h1l
            gates_mfma2<1024><<<128, 512, 0, stream>>>(
                a1h[par], a1l[par], wc1h, wc1l, b_ih1, b_hh1, c1, h1,
                a1h[par ^ 1], a1l[par ^ 1], 1024, 512,
                h1h, h1l, 512, 0);
        } else {
            lstm_gates<<<dim3(16, 16), 256, 0, stream>>>(xb, XDIM, w_ih0, h0, HH, w_hh0, 12, P);
            lstm_act<<<128, 256, 0, stream>>>(P, 16, b_ih0, b_hh0, c0, h0, nullptr, nullptr);
            lstm_gates<<<dim3(16, 8), 256, 0, stream>>>(h0, HH, w_ih1, h1, HH, w_hh1, 4, P);
            lstm_act<<<128, 256, 0, stream>>>(P, 8, b_ih1, b_hh1, c1, h1,
                                              can_split ? h1h : nullptr, h1l);
        }

        float* Lt   = buffered ? (wlog + (long)t * BB * VV) : (out + t);
        long   ldm  = buffered ? (long)VV : (long)VV * NSTEP;
        long   ldn  = buffered ? 1L : (long)NSTEP;
        float* Cbase = buffered ? (wlog + (long)t * BB * VV) : out;
        long   coff = buffered ? 0L : (long)t;

        if (can_split) {
            logits_mfma<<<250, 256, 0, stream>>>(h1h, h1l, wh, wl, b_out,
                                                 Cbase, ldm, ldn, coff);
        } else {
            gemm_kernel<1><<<dim3(250, 1), 256, 0, stream>>>(
                h1, w_out, b_out, Cbase, BB, VV, HH, ldm, ldn, coff);
        }
        argmax_kernel<<<BB, 256, 0, stream>>>(Lt, buffered ? (long)VV : (long)VV * NSTEP,
                                              ldn, pred);
    }
    if (buffered)
        transpose_out<<<dim3(BB, VV / 128), 256, 0, stream>>>(wlog, out);
}

// Round 6
// 3561.798 us; speedup vs baseline: 2.1035x; 1.2642x over previous
//
#include <hip/hip_runtime.h>
#include <math.h>

#define BB 64
#define SS 128
#define DD 1024
#define HH 512
#define EE 512
#define VV 32000
#define NSTEP 31
#define G4 2048        // 4*H
#define XDIM 1536      // E + D_enc

// ---------------- workspace layout (in floats) ----------------
#define OFF_KEYS   0L                                  // W2/v2/b2/s0
#define OFF_K2     8388608L
#define OFF_SB     12582912L
#define OFF_MA     12591104L
#define OFF_STATE  12599296L                           // h0,c0,h1,c1 (131072)
#define OFF_X      12730368L
#define OFF_P      12828672L                           // fallback P; fused: argmax slots
#define OFF_PRED   14925824L
#define OFF_WH     14925888L
#define OFF_WL     23117888L
#define OFF_H1H    31309888L
#define OFF_H1L    31326272L
#define OFF_LOG    31342656L                           // 63488000
#define TOTAL_BUF  94830656L
#define TOTAL_FB   31342656L
// ---- fused-MFMA LSTM extras (beyond TOTAL_BUF) ----
#define OFF_WC0H   94830656L                           // 2048x2048 bf16 hi (2097152 fl)
#define OFF_WC0L   96927808L
#define OFF_WC1H   99024960L                           // 2048x1024 bf16 hi (1048576 fl)
#define OFF_WC1L   100073536L
#define OFF_A0     101122112L                          // 2 par x (hi 65536 + lo 65536) fl
#define OFF_A1     101384256L                          // 2 par x (hi 32768 + lo 32768) fl
#define TOTAL_MF   101515328L

typedef __attribute__((ext_vector_type(8))) short short8;
typedef __attribute__((ext_vector_type(4))) float float4v;

__device__ __forceinline__ unsigned short bf16_rne(float v)
{
    unsigned u = __float_as_uint(v);
    unsigned r = (u + 0x7FFF + ((u >> 16) & 1)) >> 16;
    return (unsigned short)r;
}

// monotonic float -> uint (total order preserving for finite values)
__device__ __forceinline__ unsigned ordf(float f)
{
    unsigned u = __float_as_uint(f);
    return (u & 0x80000000u) ? ~u : (u | 0x80000000u);
}

// =====================================================================
// Generic fp32 GEMM (K2 gemm + logits fallback)
// =====================================================================
template<int BT>
__global__ __launch_bounds__(256)
void gemm_kernel(const float* __restrict__ A, const float* __restrict__ Bm,
                 const float* __restrict__ bias, float* __restrict__ C,
                 int M, int N, int K, long ldm, long ldn, long coff)
{
    __shared__ float As[32][68];
    __shared__ float Bs[32][132];
    int tid = threadIdx.x;
    int tx = tid & 15, ty = tid >> 4;
    int m0 = blockIdx.y * 64, n0 = blockIdx.x * 128;

    float acc[4][8];
#pragma unroll
    for (int i = 0; i < 4; ++i)
#pragma unroll
        for (int j = 0; j < 8; ++j) acc[i][j] = 0.0f;

    int ar = tid >> 3;          // 0..31
    int ac = (tid & 7) * 4;     // 0,4,...,28

    for (int kk = 0; kk < K; kk += 32) {
#pragma unroll
        for (int p = 0; p < 2; ++p) {
            int r = ar + p * 32;
            float4 v = *(const float4*)(A + (long)(m0 + r) * K + kk + ac);
            As[ac + 0][r] = v.x; As[ac + 1][r] = v.y;
            As[ac + 2][r] = v.z; As[ac + 3][r] = v.w;
        }
        if (BT) {
#pragma unroll
            for (int p = 0; p < 4; ++p) {
                int n = ar + p * 32;
                float4 v = *(const float4*)(Bm + (long)(n0 + n) * K + kk + ac);
                Bs[ac + 0][n] = v.x; Bs[ac + 1][n] = v.y;
                Bs[ac + 2][n] = v.z; Bs[ac + 3][n] = v.w;
            }
        } else {
            int bn = (tid & 31) * 4;
            int bk = tid >> 5;
#pragma unroll
            for (int p = 0; p < 4; ++p) {
                int k = bk + p * 8;
                float4 v = *(const float4*)(Bm + (long)(kk + k) * N + n0 + bn);
                *(float4*)&Bs[k][bn] = v;
            }
        }
        __syncthreads();
#pragma unroll
        for (int k = 0; k < 32; ++k) {
            float4 a  = *(const float4*)&As[k][ty * 4];
            float4 b0 = *(const float4*)&Bs[k][tx * 8];
            float4 b1 = *(const float4*)&Bs[k][tx * 8 + 4];
            float av[4] = {a.x, a.y, a.z, a.w};
            float bv[8] = {b0.x, b0.y, b0.z, b0.w, b1.x, b1.y, b1.z, b1.w};
#pragma unroll
            for (int im = 0; im < 4; ++im)
#pragma unroll
                for (int in = 0; in < 8; ++in)
                    acc[im][in] = fmaf(av[im], bv[in], acc[im][in]);
        }
        __syncthreads();
    }

#pragma unroll
    for (int im = 0; im < 4; ++im) {
        int m = m0 + ty * 4 + im;
#pragma unroll
        for (int in = 0; in < 8; ++in) {
            int n = n0 + tx * 8 + in;
            float r = acc[im][in];
            if (bias) r += bias[n];
            C[coff + (long)m * ldm + (long)n * ldn] = r;
        }
    }
}

// =====================================================================
// W2 = wk^T @ wq   (TN gemm)
// =====================================================================
__global__ __launch_bounds__(256)
void w2_gemm(const float* __restrict__ wk, const float* __restrict__ wq,
             float* __restrict__ W2)
{
    __shared__ float As[32][36];
    __shared__ float Bs[32][68];
    int tid = threadIdx.x;
    int d0 = blockIdx.y * 32, h0 = blockIdx.x * 64;
    int tx = tid & 15, ty = tid >> 4;

    float acc[2][4];
#pragma unroll
    for (int i = 0; i < 2; ++i)
#pragma unroll
        for (int j = 0; j < 4; ++j) acc[i][j] = 0.0f;

    int le = tid >> 3;
    int ld = (tid & 7) * 4;
    int lh = (tid & 7) * 8;

    for (int e0 = 0; e0 < DD; e0 += 32) {
        float4 va = *(const float4*)(wk + (long)(e0 + le) * DD + d0 + ld);
        *(float4*)&As[le][ld] = va;
        float4 vb0 = *(const float4*)(wq + (long)(e0 + le) * HH + h0 + lh);
        float4 vb1 = *(const float4*)(wq + (long)(e0 + le) * HH + h0 + lh + 4);
        *(float4*)&Bs[le][lh] = vb0;
        *(float4*)&Bs[le][lh + 4] = vb1;
        __syncthreads();
#pragma unroll
        for (int k = 0; k < 32; ++k) {
            float a0 = As[k][ty * 2];
            float a1 = As[k][ty * 2 + 1];
            float4 b = *(const float4*)&Bs[k][tx * 4];
            float bv[4] = {b.x, b.y, b.z, b.w};
#pragma unroll
            for (int j = 0; j < 4; ++j) {
                acc[0][j] = fmaf(a0, bv[j], acc[0][j]);
                acc[1][j] = fmaf(a1, bv[j], acc[1][j]);
            }
        }
        __syncthreads();
    }
#pragma unroll
    for (int i = 0; i < 2; ++i)
#pragma unroll
        for (int j = 0; j < 4; ++j)
            W2[(long)(d0 + ty * 2 + i) * HH + h0 + tx * 4 + j] = acc[i][j];
}

// v2[d] = wk^T @ bq ; b2[h] = bk @ wq ; s0 = bk . bq
__global__ __launch_bounds__(256)
void prep_vecs(const float* __restrict__ wk, const float* __restrict__ wq,
               const float* __restrict__ bq, const float* __restrict__ bk,
               float* __restrict__ v2, float* __restrict__ b2,
               float* __restrict__ s0)
{
    int idx = blockIdx.x * 256 + threadIdx.x;
    if (idx < DD) {
        float a = 0;
        for (int e = 0; e < DD; ++e) a += wk[(long)e * DD + idx] * bq[e];
        v2[idx] = a;
    } else if (idx < DD + HH) {
        int h = idx - DD;
        float a = 0;
        for (int e = 0; e < DD; ++e) a += bk[e] * wq[(long)e * HH + h];
        b2[h] = a;
    } else if (idx == DD + HH) {
        float a = 0;
        for (int e = 0; e < DD; ++e) a += bk[e] * bq[e];
        *s0 = a;
    }
}

// ---- bf16 hi/lo split of an fp32 array ----
__global__ __launch_bounds__(256)
void split_kernel(const float* __restrict__ x, unsigned short* __restrict__ hi,
                  unsigned short* __restrict__ lo, int n)
{
    int i = (blockIdx.x * 256 + threadIdx.x) * 4;
    if (i >= n) return;
    float4 v = *(const float4*)(x + i);
    float vv[4] = {v.x, v.y, v.z, v.w};
    unsigned hpack[2], lpack[2];
#pragma unroll
    for (int p = 0; p < 2; ++p) {
        unsigned short h0 = bf16_rne(vv[2 * p]);
        unsigned short h1 = bf16_rne(vv[2 * p + 1]);
        float f0 = __uint_as_float((unsigned)h0 << 16);
        float f1 = __uint_as_float((unsigned)h1 << 16);
        unsigned short l0 = bf16_rne(vv[2 * p] - f0);
        unsigned short l1 = bf16_rne(vv[2 * p + 1] - f1);
        hpack[p] = (unsigned)h0 | ((unsigned)h1 << 16);
        lpack[p] = (unsigned)l0 | ((unsigned)l1 << 16);
    }
    *(uint2*)(hi + i) = make_uint2(hpack[0], hpack[1]);
    *(uint2*)(lo + i) = make_uint2(lpack[0], lpack[1]);
}

// ---- gate-interleaved concat + bf16 hi/lo split ----
__global__ __launch_bounds__(256)
void cat_split_ilv(const float* __restrict__ s1, int K1, const float* __restrict__ s2,
                   int KK, unsigned short* __restrict__ hi, unsigned short* __restrict__ lo,
                   int total)
{
    int e = (blockIdx.x * 256 + threadIdx.x) * 4;
    if (e >= total) return;
    int r = e / KK, k = e - r * KK;
    int g = r & 3, j = r >> 2;
    int srow = g * 512 + j;
    const float* src = (k < K1) ? (s1 + (long)srow * K1 + k)
                                : (s2 + (long)srow * (KK - K1) + (k - K1));
    float4 v = *(const float4*)src;
    float vv[4] = {v.x, v.y, v.z, v.w};
    unsigned hpack[2], lpack[2];
#pragma unroll
    for (int p = 0; p < 2; ++p) {
        unsigned short h0 = bf16_rne(vv[2 * p]);
        unsigned short h1 = bf16_rne(vv[2 * p + 1]);
        float f0 = __uint_as_float((unsigned)h0 << 16);
        float f1 = __uint_as_float((unsigned)h1 << 16);
        unsigned short l0 = bf16_rne(vv[2 * p] - f0);
        unsigned short l1 = bf16_rne(vv[2 * p + 1] - f1);
        hpack[p] = (unsigned)h0 | ((unsigned)h1 << 16);
        lpack[p] = (unsigned)l0 | ((unsigned)l1 << 16);
    }
    *(uint2*)(hi + e) = make_uint2(hpack[0], hpack[1]);
    *(uint2*)(lo + e) = make_uint2(lpack[0], lpack[1]);
}

__global__ __launch_bounds__(256)
void zero_a(float* __restrict__ p)
{
    p[blockIdx.x * 256 + threadIdx.x] = 0.0f;
}

// =====================================================================
// Logits GEMM via bf16-split MFMA (3-term) — fallback (separate argmax)
// =====================================================================
__global__ __launch_bounds__(256)
void logits_mfma(const unsigned short* __restrict__ Ah, const unsigned short* __restrict__ Al,
                 const unsigned short* __restrict__ Bh, const unsigned short* __restrict__ Bl,
                 const float* __restrict__ bias, float* __restrict__ C,
                 long ldm, long ldn, long coff)
{
    int tid = threadIdx.x;
    int wid = tid >> 6, lane = tid & 63;
    int ln = lane & 15, q = lane >> 4;
    int nb = blockIdx.x * 128 + wid * 32;

    float4v acc[4][2];
#pragma unroll
    for (int mf = 0; mf < 4; ++mf)
#pragma unroll
        for (int nf = 0; nf < 2; ++nf)
            acc[mf][nf] = (float4v){0.f, 0.f, 0.f, 0.f};

    const int kb = q * 8;
#pragma unroll 2
    for (int k0 = 0; k0 < 512; k0 += 32) {
        long ko = k0 + kb;
        short8 a_h[4], a_l[4], b_h[2], b_l[2];
#pragma unroll
        for (int nf = 0; nf < 2; ++nf) {
            long row = (long)(nb + nf * 16 + ln) * 512 + ko;
            b_h[nf] = *(const short8*)(Bh + row);
            b_l[nf] = *(const short8*)(Bl + row);
        }
#pragma unroll
        for (int mf = 0; mf < 4; ++mf) {
            long row = (long)(mf * 16 + ln) * 512 + ko;
            a_h[mf] = *(const short8*)(Ah + row);
            a_l[mf] = *(const short8*)(Al + row);
        }
#pragma unroll
        for (int mf = 0; mf < 4; ++mf)
#pragma unroll
            for (int nf = 0; nf < 2; ++nf) {
                acc[mf][nf] = __builtin_amdgcn_mfma_f32_16x16x32_bf16(a_h[mf], b_h[nf], acc[mf][nf], 0, 0, 0);
                acc[mf][nf] = __builtin_amdgcn_mfma_f32_16x16x32_bf16(a_l[mf], b_h[nf], acc[mf][nf], 0, 0, 0);
                acc[mf][nf] = __builtin_amdgcn_mfma_f32_16x16x32_bf16(a_h[mf], b_l[nf], acc[mf][nf], 0, 0, 0);
            }
    }

#pragma unroll
    for (int nf = 0; nf < 2; ++nf) {
        int n = nb + nf * 16 + ln;
        float bo = bias[n];
#pragma unroll
        for (int mf = 0; mf < 4; ++mf)
#pragma unroll
            for (int r = 0; r < 4; ++r) {
                int m = mf * 16 + q * 4 + r;
                C[coff + (long)m * ldm + (long)n * ldn] = acc[mf][nf][r] + bo;
            }
    }
}

// =====================================================================
// Logits + fused argmax (fused path). C layout fixed: C[m*VV + n].
// =====================================================================
__global__ __launch_bounds__(256)
void logits_am(const unsigned short* __restrict__ Ah, const unsigned short* __restrict__ Al,
               const unsigned short* __restrict__ Bh, const unsigned short* __restrict__ Bl,
               const float* __restrict__ bias, float* __restrict__ C,
               unsigned long long* __restrict__ slot)
{
    __shared__ unsigned long long red[64][4];
    int tid = threadIdx.x;
    int wid = tid >> 6, lane = tid & 63;
    int ln = lane & 15, q = lane >> 4;
    int nb = blockIdx.x * 128 + wid * 32;

    float4v acc[4][2];
#pragma unroll
    for (int mf = 0; mf < 4; ++mf)
#pragma unroll
        for (int nf = 0; nf < 2; ++nf)
            acc[mf][nf] = (float4v){0.f, 0.f, 0.f, 0.f};

    const int kb = q * 8;
#pragma unroll 2
    for (int k0 = 0; k0 < 512; k0 += 32) {
        long ko = k0 + kb;
        short8 a_h[4], a_l[4], b_h[2], b_l[2];
#pragma unroll
        for (int nf = 0; nf < 2; ++nf) {
            long row = (long)(nb + nf * 16 + ln) * 512 + ko;
            b_h[nf] = *(const short8*)(Bh + row);
            b_l[nf] = *(const short8*)(Bl + row);
        }
#pragma unroll
        for (int mf = 0; mf < 4; ++mf) {
            long row = (long)(mf * 16 + ln) * 512 + ko;
            a_h[mf] = *(const short8*)(Ah + row);
            a_l[mf] = *(const short8*)(Al + row);
        }
#pragma unroll
        for (int mf = 0; mf < 4; ++mf)
#pragma unroll
            for (int nf = 0; nf < 2; ++nf) {
                acc[mf][nf] = __builtin_amdgcn_mfma_f32_16x16x32_bf16(a_h[mf], b_h[nf], acc[mf][nf], 0, 0, 0);
                acc[mf][nf] = __builtin_amdgcn_mfma_f32_16x16x32_bf16(a_l[mf], b_h[nf], acc[mf][nf], 0, 0, 0);
                acc[mf][nf] = __builtin_amdgcn_mfma_f32_16x16x32_bf16(a_h[mf], b_l[nf], acc[mf][nf], 0, 0, 0);
            }
    }

    float bo[2];
#pragma unroll
    for (int nf = 0; nf < 2; ++nf) bo[nf] = bias[nb + nf * 16 + ln];

#pragma unroll
    for (int mf = 0; mf < 4; ++mf)
#pragma unroll
        for (int r = 0; r < 4; ++r) {
            int m = mf * 16 + q * 4 + r;
            unsigned long long best = 0;
#pragma unroll
            for (int nf = 0; nf < 2; ++nf) {
                int n = nb + nf * 16 + ln;
                float val = acc[mf][nf][r] + bo[nf];
                C[(long)m * VV + n] = val;
                unsigned long long key =
                    ((unsigned long long)ordf(val) << 32) |
                    (unsigned long long)(0xFFFFFFFFu - (unsigned)n);
                if (key > best) best = key;
            }
#pragma unroll
            for (int o = 1; o < 16; o <<= 1) {
                unsigned long long other = __shfl_xor(best, o);
                if (other > best) best = other;
            }
            if (ln == 0) red[m][wid] = best;
        }
    __syncthreads();
    if (tid < 64) {
        unsigned long long k0v = red[tid][0], k1v = red[tid][1];
        unsigned long long k2v = red[tid][2], k3v = red[tid][3];
        unsigned long long k = k0v > k1v ? k0v : k1v;
        if (k2v > k) k = k2v;
        if (k3v > k) k = k3v;
        atomicMax(&slot[tid], k);
    }
}

// =====================================================================
// Fused LSTM layer v2 (verified round 4)
// =====================================================================
template<int KK>
__global__ __launch_bounds__(512)
void gates_mfma2(const unsigned short* __restrict__ Ah, const unsigned short* __restrict__ Al,
                 const unsigned short* __restrict__ Wh, const unsigned short* __restrict__ Wl,
                 const float* __restrict__ b_ih, const float* __restrict__ b_hh,
                 float* __restrict__ c, float* __restrict__ hout,
                 unsigned short* __restrict__ d1h, unsigned short* __restrict__ d1l,
                 int d1ld, int d1off,
                 unsigned short* __restrict__ d2h, unsigned short* __restrict__ d2l,
                 int d2ld, int d2off)
{
    __shared__ float gacc[8][64][17];
    int tid = threadIdx.x;
    int kw = tid >> 6, lane = tid & 63;
    int ln = lane & 15, q = lane >> 4;
    int nf = blockIdx.x;
    const int KS = KK / 8;
    const int kbase = kw * KS;
    long wrow = (long)(nf * 16 + ln) * KK;

    float4v acc[4];
#pragma unroll
    for (int mf = 0; mf < 4; ++mf) acc[mf] = (float4v){0.f, 0.f, 0.f, 0.f};

    const int kb = q * 8;
#pragma unroll 2
    for (int k0 = 0; k0 < KS; k0 += 32) {
        long ko = kbase + k0 + kb;
        short8 b_h = *(const short8*)(Wh + wrow + ko);
        short8 b_l = *(const short8*)(Wl + wrow + ko);
        short8 a_h[4], a_l[4];
#pragma unroll
        for (int mf = 0; mf < 4; ++mf) {
            long arow = (long)(mf * 16 + ln) * KK + ko;
            a_h[mf] = *(const short8*)(Ah + arow);
            a_l[mf] = *(const short8*)(Al + arow);
        }
#pragma unroll
        for (int mf = 0; mf < 4; ++mf) {
            acc[mf] = __builtin_amdgcn_mfma_f32_16x16x32_bf16(a_h[mf], b_h, acc[mf], 0, 0, 0);
            acc[mf] = __builtin_amdgcn_mfma_f32_16x16x32_bf16(a_l[mf], b_h, acc[mf], 0, 0, 0);
            acc[mf] = __builtin_amdgcn_mfma_f32_16x16x32_bf16(a_h[mf], b_l, acc[mf], 0, 0, 0);
            acc[mf] = __builtin_amdgcn_mfma_f32_16x16x32_bf16(a_l[mf], b_l, acc[mf], 0, 0, 0);
        }
    }

#pragma unroll
    for (int mf = 0; mf < 4; ++mf)
#pragma unroll
        for (int r = 0; r < 4; ++r)
            gacc[kw][mf * 16 + q * 4 + r][ln] = acc[mf][r];
    __syncthreads();

    if (tid < 256) {
        int m = tid >> 2, jj = tid & 3;
        int J = nf * 4 + jj;
        float gv[4];
#pragma unroll
        for (int g = 0; g < 4; ++g) {
            float v = 0;
#pragma unroll
            for (int w = 0; w < 8; ++w) v += gacc[w][m][jj * 4 + g];
            gv[g] = v + b_ih[g * HH + J] + b_hh[g * HH + J];
        }
        float i_ = 1.0f / (1.0f + expf(-gv[0]));
        float f_ = 1.0f / (1.0f + expf(-gv[1]));
        float g_ = tanhf(gv[2]);
        float o_ = 1.0f / (1.0f + expf(-gv[3]));
        int ci = m * HH + J;
        float cn = f_ * c[ci] + i_ * g_;
        c[ci] = cn;
        float hv = o_ * tanhf(cn);
        if (hout) hout[ci] = hv;
        unsigned short hb = bf16_rne(hv);
        float hf = __uint_as_float((unsigned)hb << 16);
        unsigned short lb = bf16_rne(hv - hf);
        d1h[m * d1ld + d1off + J] = hb;
        d1l[m * d1ld + d1off + J] = lb;
        if (d2h) {
            d2h[m * d2ld + d2off + J] = hb;
            d2l[m * d2ld + d2off + J] = lb;
        }
    }
}

// =====================================================================
// LSTM gates split-K GEMM (fallback path)
// =====================================================================
__global__ __launch_bounds__(256)
void lstm_gates(const float* __restrict__ A1, int K1, const float* __restrict__ B1,
                const float* __restrict__ A2, int K2c, const float* __restrict__ B2,
                int z1, float* __restrict__ P)
{
    __shared__ float As[32][68];
    __shared__ float Bs[32][132];
    int tid = threadIdx.x;
    int tx = tid & 15, ty = tid >> 4;
    int n0 = blockIdx.x * 128;
    int z = blockIdx.y;

    const float* A; const float* Bw; int kb, lda;
    if (z < z1) { A = A1; Bw = B1; kb = z * 128;        lda = K1; }
    else        { A = A2; Bw = B2; kb = (z - z1) * 128; lda = K2c; }

    float acc[4][8];
#pragma unroll
    for (int i = 0; i < 4; ++i)
#pragma unroll
        for (int j = 0; j < 8; ++j) acc[i][j] = 0.0f;

    int ar = tid >> 3;
    int ac = (tid & 7) * 4;

    for (int kk = kb; kk < kb + 128; kk += 32) {
#pragma unroll
        for (int p = 0; p < 2; ++p) {
            int r = ar + p * 32;
            float4 v = *(const float4*)(A + (long)r * lda + kk + ac);
            As[ac + 0][r] = v.x; As[ac + 1][r] = v.y;
            As[ac + 2][r] = v.z; As[ac + 3][r] = v.w;
        }
#pragma unroll
        for (int p = 0; p < 4; ++p) {
            int n = ar + p * 32;
            float4 v = *(const float4*)(Bw + (long)(n0 + n) * lda + kk + ac);
            Bs[ac + 0][n] = v.x; Bs[ac + 1][n] = v.y;
            Bs[ac + 2][n] = v.z; Bs[ac + 3][n] = v.w;
        }
        __syncthreads();
#pragma unroll
        for (int k = 0; k < 32; ++k) {
            float4 a  = *(const float4*)&As[k][ty * 4];
            float4 b0 = *(const float4*)&Bs[k][tx * 8];
            float4 b1 = *(const float4*)&Bs[k][tx * 8 + 4];
            float av[4] = {a.x, a.y, a.z, a.w};
            float bv[8] = {b0.x, b0.y, b0.z, b0.w, b1.x, b1.y, b1.z, b1.w};
#pragma unroll
            for (int im = 0; im < 4; ++im)
#pragma unroll
                for (int in = 0; in < 8; ++in)
                    acc[im][in] = fmaf(av[im], bv[in], acc[im][in]);
        }
        __syncthreads();
    }

    float* Pp = P + (long)z * (BB * (long)G4);
#pragma unroll
    for (int im = 0; im < 4; ++im) {
        int m = ty * 4 + im;
#pragma unroll
        for (int in = 0; in < 8; ++in)
            Pp[(long)m * G4 + n0 + tx * 8 + in] = acc[im][in];
    }
}

// ---- fallback act ----
__global__ __launch_bounds__(256)
void lstm_act(const float* __restrict__ P, int z,
              const float* __restrict__ b_ih, const float* __restrict__ b_hh,
              float* __restrict__ c, float* __restrict__ h,
              unsigned short* __restrict__ hh, unsigned short* __restrict__ hl)
{
    int idx = blockIdx.x * 256 + threadIdx.x;
    int b = idx >> 9, j = idx & 511;
    float gi = 0, gf = 0, gg = 0, go = 0;
    for (int zi = 0; zi < z; ++zi) {
        const float* p = P + (long)zi * (BB * (long)G4) + (long)b * G4 + j;
        gi += p[0]; gf += p[HH]; gg += p[2 * HH]; go += p[3 * HH];
    }
    gi += b_ih[j] + b_hh[j];
    gf += b_ih[HH + j] + b_hh[HH + j];
    gg += b_ih[2 * HH + j] + b_hh[2 * HH + j];
    go += b_ih[3 * HH + j] + b_hh[3 * HH + j];
    float i_ = 1.0f / (1.0f + expf(-gi));
    float f_ = 1.0f / (1.0f + expf(-gf));
    float g_ = tanhf(gg);
    float o_ = 1.0f / (1.0f + expf(-go));
    float cn = f_ * c[idx] + i_ * g_;
    c[idx] = cn;
    float hv = o_ * tanhf(cn);
    h[idx] = hv;
    if (hh) {
        unsigned short hb = bf16_rne(hv);
        float hf = __uint_as_float((unsigned)hb << 16);
        hh[idx] = hb;
        hl[idx] = bf16_rne(hv - hf);
    }
}

// =====================================================================
// attn_embed v2: 1024 threads, grid (b x 4 d-chunks).
// =====================================================================
__global__ __launch_bounds__(1024)
void attn_embed(const float* __restrict__ h1, const float* __restrict__ K2,
                const float* __restrict__ sb, const float* __restrict__ mA,
                const float* __restrict__ enc, const float* __restrict__ emb,
                const int* __restrict__ pred, const unsigned long long* __restrict__ am,
                float* __restrict__ x,
                unsigned short* __restrict__ a0h, unsigned short* __restrict__ a0l)
{
    __shared__ float shH[512];
    __shared__ float shP[128][9];
    __shared__ float shS[128];
    __shared__ float shC[4][256];
    __shared__ float shB[2];
    int b = blockIdx.x >> 2, ch = blockIdx.x & 3;
    int tid = threadIdx.x;

    if (tid < 512) shH[tid] = h1[b * HH + tid];
    if (ch == 0 && tid < 512) {
        int pv = am ? (int)(0xFFFFFFFFu - (unsigned)(am[b] & 0xFFFFFFFFull))
                    : pred[b];
        float v = emb[(long)pv * EE + tid];
        if (x) x[(long)b * XDIM + tid] = v;
        if (a0h) {
            unsigned short hb = bf16_rne(v);
            a0h[b * 2048 + tid] = hb;
            a0l[b * 2048 + tid] = bf16_rne(v - __uint_as_float((unsigned)hb << 16));
        }
    }
    __syncthreads();

    // scores: (s, oct) decomposition, 64-length sub-dots
    {
        int s = tid >> 3, oct = tid & 7;
        const float* kp = K2 + ((long)(b * SS + s)) * HH + oct * 64;
        const float* hp = shH + oct * 64;
        float a = 0;
#pragma unroll 4
        for (int j = 0; j < 64; j += 4) {
            float4 v = *(const float4*)(kp + j);
            a += hp[j] * v.x + hp[j + 1] * v.y + hp[j + 2] * v.z + hp[j + 3] * v.w;
        }
        shP[s][oct] = a;
    }
    __syncthreads();
    if (tid < 128) {
        float t8 = 0;
#pragma unroll
        for (int o = 0; o < 8; ++o) t8 += shP[tid][o];
        shS[tid] = (t8 + sb[b * SS + tid]) * 0.03125f + mA[b * SS + tid];
    }
    __syncthreads();
    if (tid < 64) {
        float v = fmaxf(shS[tid], shS[tid + 64]);
#pragma unroll
        for (int o = 1; o < 64; o <<= 1) v = fmaxf(v, __shfl_xor(v, o));
        if (tid == 0) shB[0] = v;
    }
    __syncthreads();
    if (tid < 128) shS[tid] = expf(shS[tid] - shB[0]);
    __syncthreads();
    if (tid < 64) {
        float v = shS[tid] + shS[tid + 64];
#pragma unroll
        for (int o = 1; o < 64; o <<= 1) v += __shfl_xor(v, o);
        if (tid == 0) shB[1] = 1.0f / v;
    }
    __syncthreads();
    if (tid < 128) shS[tid] *= shB[1];
    __syncthreads();

    // ctx: (s-quarter, d-col) decomposition
    {
        int sq = tid >> 8, dl = tid & 255;
        const float* ep = enc + (long)b * SS * DD + (long)(sq * 32) * DD + ch * 256 + dl;
        float a = 0;
#pragma unroll 4
        for (int s = 0; s < 32; ++s)
            a += shS[sq * 32 + s] * ep[(long)s * DD];
        shC[sq][dl] = a;
    }
    __syncthreads();
    if (tid < 256) {
        float a = ((shC[0][tid] + shC[1][tid]) + shC[2][tid]) + shC[3][tid];
        int col = EE + ch * 256 + tid;
        if (x) x[(long)b * XDIM + col] = a;
        if (a0h) {
            unsigned short hb = bf16_rne(a);
            a0h[b * 2048 + col] = hb;
            a0l[b * 2048 + col] = bf16_rne(a - __uint_as_float((unsigned)hb << 16));
        }
    }
}

// ---- greedy argmax (fallback path only) ----
__global__ __launch_bounds__(256)
void argmax_kernel(const float* __restrict__ L, long rowStride, long vStride,
                   int* __restrict__ pred)
{
    __shared__ float shV[256];
    __shared__ int   shI[256];
    int b = blockIdx.x, tid = threadIdx.x;
    const float* p = L + (long)b * rowStride;
    float best = -INFINITY; int bi = 0;
    for (int v = tid; v < VV; v += 256) {
        float val = p[(long)v * vStride];
        if (val > best) { best = val; bi = v; }
    }
    shV[tid] = best; shI[tid] = bi;
    __syncthreads();
    for (int o = 128; o > 0; o >>= 1) {
        if (tid < o) {
            float ov = shV[tid + o]; int oi = shI[tid + o];
            if (ov > shV[tid] || (ov == shV[tid] && oi < shI[tid])) {
                shV[tid] = ov; shI[tid] = oi;
            }
        }
        __syncthreads();
    }
    if (tid == 0) pred[b] = shI[0];
}

// ---- (T,B,V) -> (B,V,T) transpose via LDS ----
__global__ __launch_bounds__(256)
void transpose_out(const float* __restrict__ Lall, float* __restrict__ out)
{
    __shared__ float tile[NSTEP][129];
    int b = blockIdx.x, v0 = blockIdx.y * 128, tid = threadIdx.x;
    int i = tid & 127, th = tid >> 7;
    for (int tp = 0; tp < 16; ++tp) {
        int t = th + tp * 2;
        if (t < NSTEP)
            tile[t][i] = Lall[(long)t * BB * VV + (long)b * VV + v0 + i];
    }
    __syncthreads();
    long obase = (long)b * VV * NSTEP + (long)v0 * NSTEP;
    for (int w = tid; w < 128 * NSTEP; w += 256)
        out[obase + w] = tile[w % NSTEP][w / NSTEP];
}

// ---- detect mask dtype and canonicalize ----
__global__ void mask_canon(const void* __restrict__ maskp, float* __restrict__ mA)
{
    __shared__ int ok;
    const unsigned char* bt = (const unsigned char*)maskp;
    int tid = threadIdx.x;
    if (tid == 0) ok = 1;
    __syncthreads();
    int bad = 0;
    for (int i = tid; i < BB * SS; i += 256) {
        unsigned char v = bt[i];
        if (v > 1) bad = 1;
        if ((i & (SS - 1)) != 0 && bt[i - 1] > v) bad = 1;
    }
    if (bad) atomicAnd(&ok, 0);
    __syncthreads();
    int packed = ok;
    const int* wi = (const int*)maskp;
    for (int i = tid; i < BB * SS; i += 256) {
        int m = packed ? (bt[i] != 0) : (wi[i] != 0);
        mA[i] = m ? -1.0e10f : 0.0f;
    }
}

// ---- init state + pred + argmax slots (slot0 = START token 1) ----
__global__ void init_state(float* __restrict__ st, int* __restrict__ pred,
                           unsigned long long* __restrict__ amu)
{
    int idx = blockIdx.x * 256 + threadIdx.x;
    st[idx] = 0.0f;
    if (idx < BB) pred[idx] = 1;
    if (idx < 2048)
        amu[idx] = (idx < 64) ? 0xFFFFFFFEull : 0ull;  // decode -> idx 1
}

// sb[b,s] = enc[b,s,:] . v2 + s0
__global__ void sb_kernel(const float* __restrict__ enc, const float* __restrict__ v2,
                          const float* __restrict__ s0, float* __restrict__ sb)
{
    int bs = blockIdx.x * 256 + threadIdx.x;
    const float* kp = enc + (long)bs * DD;
    float a = 0;
    for (int d = 0; d < DD; d += 4) {
        float4 kv = *(const float4*)(kp + d);
        float4 bv = *(const float4*)(v2 + d);
        a += kv.x * bv.x + kv.y * bv.y + kv.z * bv.z + kv.w * bv.w;
    }
    sb[bs] = a + *s0;
}

extern "C" void kernel_launch(void* const* d_in, const int* in_sizes, int n_in,
                              void* d_out, int out_size, void* d_ws, size_t ws_size,
                              hipStream_t stream)
{
    const float* enc   = (const float*)d_in[0];
    const void*  maskp = d_in[1];
    const float* embt  = (const float*)d_in[2];
    const float* wq    = (const float*)d_in[3];
    const float* bq    = (const float*)d_in[4];
    const float* wk    = (const float*)d_in[5];
    const float* bk    = (const float*)d_in[6];
    const float* w_ih0 = (const float*)d_in[7];
    const float* w_hh0 = (const float*)d_in[8];
    const float* b_ih0 = (const float*)d_in[9];
    const float* b_hh0 = (const float*)d_in[10];
    const float* w_ih1 = (const float*)d_in[11];
    const float* w_hh1 = (const float*)d_in[12];
    const float* b_ih1 = (const float*)d_in[13];
    const float* b_hh1 = (const float*)d_in[14];
    const float* w_out = (const float*)d_in[15];
    const float* b_out = (const float*)d_in[16];

    float* out  = (float*)d_out;
    float* w    = (float*)d_ws;
    float* W2   = w + OFF_KEYS;
    float* v2   = W2 + 524288;
    float* b2v  = v2 + 1024;
    float* s0   = b2v + 512;
    float* K2b  = w + OFF_K2;
    float* sbb  = w + OFF_SB;
    float* mA   = w + OFF_MA;
    float* h0   = w + OFF_STATE;
    float* c0   = h0 + BB * HH;
    float* h1   = c0 + BB * HH;
    float* c1   = h1 + BB * HH;
    float* xb   = w + OFF_X;
    float* P    = w + OFF_P;
    int*   pred = (int*)(w + OFF_PRED);
    unsigned long long* amu = (unsigned long long*)(w + OFF_P);  // fused: slots
    unsigned short* wh  = (unsigned short*)(w + OFF_WH);
    unsigned short* wl  = (unsigned short*)(w + OFF_WL);
    unsigned short* h1h = (unsigned short*)(w + OFF_H1H);
    unsigned short* h1l = (unsigned short*)(w + OFF_H1L);
    float* wlog = w + OFF_LOG;
    unsigned short* wc0h = (unsigned short*)(w + OFF_WC0H);
    unsigned short* wc0l = (unsigned short*)(w + OFF_WC0L);
    unsigned short* wc1h = (unsigned short*)(w + OFF_WC1H);
    unsigned short* wc1l = (unsigned short*)(w + OFF_WC1L);

    bool can_split = ws_size >= (size_t)TOTAL_FB * 4;
    bool buffered  = ws_size >= (size_t)TOTAL_BUF * 4;
    bool fused     = buffered && ws_size >= (size_t)TOTAL_MF * 4;

    mask_canon<<<1, 256, 0, stream>>>(maskp, mA);
    init_state<<<512, 256, 0, stream>>>(w + OFF_STATE, pred, amu);

    prep_vecs<<<7, 256, 0, stream>>>(wk, wq, bq, bk, v2, b2v, s0);
    w2_gemm<<<dim3(8, 32), 256, 0, stream>>>(wk, wq, W2);
    gemm_kernel<0><<<dim3(4, 128), 256, 0, stream>>>(
        enc, W2, b2v, K2b, BB * SS, HH, DD, (long)HH, 1L, 0L);
    sb_kernel<<<32, 256, 0, stream>>>(enc, v2, s0, sbb);

    if (can_split)
        split_kernel<<<16000, 256, 0, stream>>>(w_out, wh, wl, VV * HH);

    if (fused) {
        cat_split_ilv<<<4096, 256, 0, stream>>>(w_ih0, XDIM, w_hh0, 2048, wc0h, wc0l,
                                                2048 * 2048);
        cat_split_ilv<<<2048, 256, 0, stream>>>(w_ih1, HH, w_hh1, 1024, wc1h, wc1l,
                                                2048 * 1024);
        zero_a<<<1536, 256, 0, stream>>>(w + OFF_A0);
    }

    for (int t = 0; t < NSTEP; ++t) {
        int par = t & 1;
        unsigned short* a0h[2], * a0l[2], * a1h[2], * a1l[2];
        for (int pp = 0; pp < 2; ++pp) {
            a0h[pp] = (unsigned short*)(w + OFF_A0 + (long)pp * 131072);
            a0l[pp] = (unsigned short*)(w + OFF_A0 + (long)pp * 131072 + 65536);
            a1h[pp] = (unsigned short*)(w + OFF_A1 + (long)pp * 65536);
            a1l[pp] = (unsigned short*)(w + OFF_A1 + (long)pp * 65536 + 32768);
        }

        attn_embed<<<BB * 4, 1024, 0, stream>>>(
            h1, K2b, sbb, mA, enc, embt, pred,
            fused ? (amu + (size_t)t * 64) : nullptr,
            fused ? nullptr : xb,
            fused ? a0h[par] : nullptr,
            fused ? a0l[par] : nullptr);

        if (fused) {
            gates_mfma2<2048><<<128, 512, 0, stream>>>(
                a0h[par], a0l[par], wc0h, wc0l, b_ih0, b_hh0, c0, nullptr,
                a0h[par ^ 1], a0l[par ^ 1], 2048, 1536,
                a1h[par], a1l[par], 1024, 0);
            gates_mfma2<1024><<<128, 512, 0, stream>>>(
                a1h[par], a1l[par], wc1h, wc1l, b_ih1, b_hh1, c1, h1,
                a1h[par ^ 1], a1l[par ^ 1], 1024, 512,
                h1h, h1l, 512, 0);
            logits_am<<<250, 256, 0, stream>>>(
                h1h, h1l, wh, wl, b_out,
                wlog + (long)t * BB * VV, amu + (size_t)(t + 1) * 64);
        } else {
            lstm_gates<<<dim3(16, 16), 256, 0, stream>>>(xb, XDIM, w_ih0, h0, HH, w_hh0, 12, P);
            lstm_act<<<128, 256, 0, stream>>>(P, 16, b_ih0, b_hh0, c0, h0, nullptr, nullptr);
            lstm_gates<<<dim3(16, 8), 256, 0, stream>>>(h0, HH, w_ih1, h1, HH, w_hh1, 4, P);
            lstm_act<<<128, 256, 0, stream>>>(P, 8, b_ih1, b_hh1, c1, h1,
                                              can_split ? h1h : nullptr, h1l);

            float* Lt    = buffered ? (wlog + (long)t * BB * VV) : (out + t);
            long   ldm   = buffered ? (long)VV : (long)VV * NSTEP;
            long   ldn   = buffered ? 1L : (long)NSTEP;
            float* Cbase = buffered ? (wlog + (long)t * BB * VV) : out;
            long   coff  = buffered ? 0L : (long)t;

            if (can_split) {
                logits_mfma<<<250, 256, 0, stream>>>(h1h, h1l, wh, wl, b_out,
                                                     Cbase, ldm, ldn, coff);
            } else {
                gemm_kernel<1><<<dim3(250, 1), 256, 0, stream>>>(
                    h1, w_out, b_out, Cbase, BB, VV, HH, ldm, ldn, coff);
            }
            argmax_kernel<<<BB, 256, 0, stream>>>(Lt, buffered ? (long)VV : (long)VV * NSTEP,
                                                  ldn, pred);
        }
    }
    if (buffered)
        transpose_out<<<dim3(BB, VV / 128), 256, 0, stream>>>(wlog, out);
}